// Round 14
// baseline (352.095 us; speedup 1.0000x reference)
//
#include <hip/hip_runtime.h>
#include <hip/hip_cooperative_groups.h>

// QMN B=32,T=60,D=128. Round 24: cooperative pow2-tail + meas NB=8.
//  - k_powgchain (cooperative, 60 blk): s=3,4,5 on blocks 0-15 with
//    grid.sync() between, then gchain on all 60. 4 launches -> 1 (14 -> 11).
//  - k_meas v7: NB=8 (480 blk = 60t x 2h x 4g); V staged once per block,
//    8 b's looped; delivered bytes 156 -> 138MB. raw = h*240 + t*4 + g keeps
//    h-siblings on the same XCD (240 % 8 == 0).
// Everything else = r23.

#define DB 32
#define DT 60
#define DD 128
#define BT (DB*DT)
#define SP 136

namespace cg = cooperative_groups;

typedef unsigned short ushort_t;
typedef __attribute__((ext_vector_type(8))) __bf16 bf16x8;
typedef __attribute__((ext_vector_type(8))) unsigned short ushort8_t;
typedef __attribute__((ext_vector_type(4))) float  float4v;

__device__ __forceinline__ float bf2f(ushort_t u){
  union { unsigned int i; float f; } x; x.i = ((unsigned int)u) << 16; return x.f;
}
__device__ __forceinline__ ushort_t f2bf(float f){
  union { float f; unsigned int i; } x; x.f = f;
  unsigned int lsb = (x.i >> 16) & 1u;
  return (ushort_t)((x.i + 0x7FFFu + lsb) >> 16);
}
__device__ __forceinline__ unsigned int f2bfpk(float a, float b){
#if defined(__gfx950__) && __has_builtin(__builtin_amdgcn_cvt_pk_bf16_f32)
  auto v = __builtin_amdgcn_cvt_pk_bf16_f32(a, b);
  unsigned int r; __builtin_memcpy(&r, &v, 4); return r;
#else
  return (unsigned int)f2bf(a) | ((unsigned int)f2bf(b) << 16);
#endif
}
__device__ __forceinline__ void split2(float v, ushort_t& h, ushort_t& l){
  h = f2bf(v); l = f2bf(v - bf2f(h));
}

// D[m][n] = sum_k A[m][k]*B[n][k]
template<int RT, int CT, bool ALO, bool BLO>
__device__ __forceinline__ void gemm_t(const ushort_t* Ah, const ushort_t* Al,
                                       const ushort_t* Bh, const ushort_t* Bl,
                                       float4v* acc, int row0, int col0, int gma, int q)
{
  for (int ks = 0; ks < 4; ks++){
    int ko = ks*32 + q*8;
    bf16x8 aF[RT], aL[RT], bF[CT], bL[CT];
    #pragma unroll
    for (int R = 0; R < RT; R++){
      int row = row0 + 16*R + gma;
      aF[R] = *(const bf16x8*)&Ah[row*SP + ko];
      if (ALO) aL[R] = *(const bf16x8*)&Al[row*SP + ko];
    }
    #pragma unroll
    for (int C = 0; C < CT; C++){
      int row = col0 + 16*C + gma;
      bF[C] = *(const bf16x8*)&Bh[row*SP + ko];
      if (BLO) bL[C] = *(const bf16x8*)&Bl[row*SP + ko];
    }
    #pragma unroll
    for (int R = 0; R < RT; R++)
      #pragma unroll
      for (int C = 0; C < CT; C++){
        float4v c = acc[R*CT+C];
        c = __builtin_amdgcn_mfma_f32_16x16x32_bf16(aF[R], bF[C], c, 0, 0, 0);
        if (BLO) c = __builtin_amdgcn_mfma_f32_16x16x32_bf16(aF[R], bL[C], c, 0, 0, 0);
        if (ALO) c = __builtin_amdgcn_mfma_f32_16x16x32_bf16(aL[R], bF[C], c, 0, 0, 0);
        acc[R*CT+C] = c;
      }
  }
}

// transposed store computed(m,n) -> dst[n*stride + m]
template<int RT, int CT>
__device__ __forceinline__ void emit_t(const float4v* acc, ushort_t* dst, int stride,
                                       int row0, int col0, int gma, int q){
  #pragma unroll
  for (int R = 0; R < RT; R++)
    #pragma unroll
    for (int C = 0; C < CT; C++){
      int c = col0 + 16*C + gma, r0 = row0 + 16*R + 4*q;
      uint2 o;
      o.x = f2bfpk(acc[R*CT+C][0], acc[R*CT+C][1]);
      o.y = f2bfpk(acc[R*CT+C][2], acc[R*CT+C][3]);
      *(uint2*)&dst[(size_t)c*stride + r0] = o;
    }
}
template<int RT, int CT>
__device__ __forceinline__ void emit_split_t(const float4v* acc, ushort_t* dh, ushort_t* dl, int stride,
                                             int row0, int col0, int gma, int q){
  #pragma unroll
  for (int R = 0; R < RT; R++)
    #pragma unroll
    for (int C = 0; C < CT; C++){
      int c = col0 + 16*C + gma, r0 = row0 + 16*R + 4*q;
      ushort4 hh, ll;
      split2(acc[R*CT+C][0], hh.x, ll.x); split2(acc[R*CT+C][1], hh.y, ll.y);
      split2(acc[R*CT+C][2], hh.z, ll.z); split2(acc[R*CT+C][3], hh.w, ll.w);
      *(ushort4*)&dh[(size_t)c*stride + r0] = hh;
      *(ushort4*)&dl[(size_t)c*stride + r0] = ll;
    }
}
template<int NT>
__device__ __forceinline__ void lds_load_mat(ushort_t* dst, const ushort_t* src, int tid){
  for (int i = tid*8; i < 16384; i += NT*8){
    int r = i >> 7, k = i & 127;
    *(ushort8_t*)&dst[r*SP + k] = *(const ushort8_t*)&src[i];
  }
}
// 16 rows x 128 cols, contiguous source (2048 elems)
template<int NT>
__device__ __forceinline__ void lds_load_rows16(ushort_t* dst, const ushort_t* src, int tid){
  for (int i = tid*8; i < 2048; i += NT*8){
    int r = i >> 7, k = i & 127;
    *(ushort8_t*)&dst[r*SP + k] = *(const ushort8_t*)&src[i];
  }
}
// issue-early pair stager: all global loads issued, then all ds_writes
template<int NT>
__device__ __forceinline__ void lds_load_mat2(ushort_t* d0, const ushort_t* s0,
                                              ushort_t* d1, const ushort_t* s1, int tid){
  constexpr int CH = 16384/(NT*8);
  ushort8_t r0[CH], r1[CH];
  #pragma unroll
  for (int c = 0; c < CH; c++) r0[c] = *(const ushort8_t*)&s0[tid*8 + c*NT*8];
  #pragma unroll
  for (int c = 0; c < CH; c++) r1[c] = *(const ushort8_t*)&s1[tid*8 + c*NT*8];
  #pragma unroll
  for (int c = 0; c < CH; c++){
    int i = tid*8 + c*NT*8; int r = i >> 7, k = i & 127;
    *(ushort8_t*)&d0[r*SP + k] = r0[c];
  }
  #pragma unroll
  for (int c = 0; c < CH; c++){
    int i = tid*8 + c*NT*8; int r = i >> 7, k = i & 127;
    *(ushort8_t*)&d1[r*SP + k] = r1[c];
  }
}
template<int NT>
__device__ __forceinline__ void lds_store_mat(ushort_t* dst, const ushort_t* src, int tid){
  for (int i = tid*8; i < 16384; i += NT*8){
    int r = i >> 7, k = i & 127;
    *(ushort8_t*)&dst[i] = *(const ushort8_t*)&src[r*SP + k];
  }
}

// ---- pow2 step body (guarded for 512-thr merged launches) ----
__device__ __forceinline__ void pow2_body(int blk2, int s,
    ushort_t* PpH, ushort_t* PpL, ushort_t* PTh, ushort_t* PTl,
    int tid, ushort_t* Ah, ushort_t* Al, ushort_t* Bh, ushort_t* Bl)
{
  int which = blk2 >> 3, sl = blk2 & 7;
  size_t src = (size_t)(s-1)*16384, dst = (size_t)s*16384;
  int gcol0 = sl*16;
  const ushort_t *A_h, *A_l, *B_h, *B_l; ushort_t *D_h, *D_l;
  if (which == 0){ A_h = PTh+src; A_l = PTl+src; B_h = PpH+src; B_l = PpL+src;
                   D_h = PpH+dst; D_l = PpL+dst; }
  else           { A_h = PpH+src; A_l = PpL+src; B_h = PTh+src; B_l = PTl+src;
                   D_h = PTh+dst; D_l = PTl+dst; }
  if (tid < 256){
    lds_load_mat<256>(Ah, A_h, tid);
    lds_load_mat<256>(Al, A_l, tid);
    lds_load_rows16<256>(Bh, B_h + (size_t)gcol0*128, tid);
    lds_load_rows16<256>(Bl, B_l + (size_t)gcol0*128, tid);
  }
  __syncthreads();
  if (tid < 256){
    int w = tid >> 6, lane = tid & 63, gma = lane & 15, q = lane >> 4;
    int row0 = 32*w;
    float4v acc[2];
    acc[0] = (float4v){0.f,0.f,0.f,0.f};
    acc[1] = (float4v){0.f,0.f,0.f,0.f};
    gemm_t<2,1,true,true>(Ah, Al, Bh, Bl, acc, row0, 0, gma, q);
    emit_split_t<2,1>(acc, D_h, D_l, 128, row0, gcol0, gma, q);
  }
}

// ---- small: prepU | normv | initG | weight-transpose prep | xconv ----
__global__ void k_small(const float* Ux, const float* Uh, const float* kr, const float* ki,
                        const float* Wp0, const float* Wp1, const float* Wp2,
                        const float* x0, const float* x1, const float* x2,
                        ushort_t* UxTh, ushort_t* UxTl, ushort_t* UxH, ushort_t* UxL,
                        float* Vr, float* Vi,
                        ushort_t* PpH, ushort_t* PpL, ushort_t* PTh, ushort_t* PTl,
                        ushort_t* WT0h, ushort_t* WT0l, ushort_t* WT1h, ushort_t* WT1l,
                        ushort_t* WT2h, ushort_t* WT2l,
                        ushort_t* X0h, ushort_t* X0l, ushort_t* X1h, ushort_t* X1l,
                        ushort_t* X2h, ushort_t* X2l){
  int blk = blockIdx.x, d = threadIdx.x;
  if (blk < 128){
    int i = blk;
    float v = Ux[i*DD + d];
    ushort_t h, l; split2(v, h, l);
    UxTh[d*DD + i] = h; UxTl[d*DD + i] = l;
  } else if (blk < 256){
    __shared__ float red[DD];
    int k = blk - 128;
    float r = kr[k*DD+d], im = ki[k*DD+d];
    red[d] = r*r + im*im;
    __syncthreads();
    for (int s = 64; s > 0; s >>= 1){ if (d < s) red[d] += red[d+s]; __syncthreads(); }
    float nrm = fmaxf(sqrtf(red[0]), 1e-12f);
    Vr[k*DD+d] = r/nrm; Vi[k*DD+d] = im/nrm;
  } else if (blk < 384){
    int i = blk - 256;
    float v = Uh[i*DD + d];
    ushort_t h, l; split2(v, h, l);
    PpH[i*DD + d] = h;  PpL[i*DD + d] = l;
    PTh[d*DD + i] = h;  PTl[d*DD + i] = l;
  } else if (blk < 512){
    int dd2 = blk - 384;  // output row index d of WT / Ux
    ushort_t h, l;
    for (int k = d; k < 768; k += 128){
      split2(Wp0[(size_t)k*DD + dd2], h, l);
      WT0h[(size_t)dd2*768 + k] = h; WT0l[(size_t)dd2*768 + k] = l;
    }
    { float v = (d < 74) ? Wp1[(size_t)d*DD + dd2] : 0.f;
      split2(v, h, l); WT1h[dd2*128 + d] = h; WT1l[dd2*128 + d] = l; }
    { float v = (d < 35) ? Wp2[(size_t)d*DD + dd2] : 0.f;
      split2(v, h, l); WT2h[dd2*128 + d] = h; WT2l[dd2*128 + d] = l; }
    { split2(Ux[(size_t)dd2*DD + d], h, l);
      UxH[dd2*DD + d] = h; UxL[dd2*DD + d] = l; }
  } else {
    int bt = blk - 512;  // xconv
    ushort_t h, l;
    const float* r0 = x0 + (size_t)bt*768;
    #pragma unroll
    for (int j = 0; j < 6; j++){
      split2(r0[j*128 + d], h, l);
      X0h[(size_t)bt*768 + j*128 + d] = h;
      X0l[(size_t)bt*768 + j*128 + d] = l;
    }
    float v1 = (d < 74) ? x1[(size_t)bt*74 + d] : 0.f;
    split2(v1, h, l);
    X1h[(size_t)bt*128 + d] = h; X1l[(size_t)bt*128 + d] = l;
    float v2 = (d < 35) ? x2[(size_t)bt*35 + d] : 0.f;
    split2(v2, h, l);
    X2h[(size_t)bt*128 + d] = h; X2l[(size_t)bt*128 + d] = l;
  }
}

// ---- proj v3: split-K hi/lo MFMA GEMM, + pow2 s=1 piggyback ----
__global__ __launch_bounds__(512,1) void k_proj(
    const ushort_t* X0h, const ushort_t* X0l, const ushort_t* X1h, const ushort_t* X1l,
    const ushort_t* X2h, const ushort_t* X2l,
    const ushort_t* WT0h, const ushort_t* WT0l, const ushort_t* WT1h, const ushort_t* WT1l,
    const ushort_t* WT2h, const ushort_t* WT2l,
    const float* bp1, const float* bp2,
    float* Rpart, float* Reps,
    ushort_t* PpH, ushort_t* PpL, ushort_t* PTh, ushort_t* PTl)
{
  __shared__ ushort_t Ah[128*SP], Al[128*SP], Bh[128*SP], Bl[128*SP];
  int blk = blockIdx.x;
  int tid = threadIdx.x;
  if (blk >= 120){
    pow2_body(blk - 120, 1, PpH, PpL, PTh, PTl, tid, Ah, Al, Bh, Bl);
    return;
  }
  int m, tile, ch;
  if (blk < 90){ m = 0; tile = blk/6; ch = blk%6; }
  else if (blk < 105){ m = 1; tile = blk-90; ch = 0; }
  else { m = 2; tile = blk-105; ch = 0; }
  int bt0 = tile*128;
  int w = tid >> 6, lane = tid & 63, gma = lane & 15, q = lane >> 4;
  int row0 = 32*(w >> 1), col0 = 64*(w & 1);
  const ushort_t* Wh_ = (m==0)? WT0h : (m==1)? WT1h : WT2h;
  const ushort_t* Wl_ = (m==0)? WT0l : (m==1)? WT1l : WT2l;
  const ushort_t* Xh_ = (m==0)? X0h : (m==1)? X1h : X2h;
  const ushort_t* Xl_ = (m==0)? X0l : (m==1)? X1l : X2l;
  int KX = (m==0)? 768 : 128;
  for (int i = tid*8; i < 16384; i += 4096){
    int r = i >> 7, k = i & 127;
    *(ushort8_t*)&Ah[r*SP + k] = *(const ushort8_t*)&Wh_[(size_t)r*KX + ch*128 + k];
    *(ushort8_t*)&Al[r*SP + k] = *(const ushort8_t*)&Wl_[(size_t)r*KX + ch*128 + k];
    *(ushort8_t*)&Bh[r*SP + k] = *(const ushort8_t*)&Xh_[(size_t)(bt0+r)*KX + ch*128 + k];
    *(ushort8_t*)&Bl[r*SP + k] = *(const ushort8_t*)&Xl_[(size_t)(bt0+r)*KX + ch*128 + k];
  }
  __syncthreads();
  float4v acc[8];
  #pragma unroll
  for (int i = 0; i < 8; i++) acc[i] = (float4v){0.f,0.f,0.f,0.f};
  gemm_t<2,4,true,true>(Ah, Al, Bh, Bl, acc, row0, col0, gma, q);
  if (m == 0){
    #pragma unroll
    for (int R = 0; R < 2; R++)
      #pragma unroll
      for (int C = 0; C < 4; C++){
        int c = col0 + 16*C + gma, r0 = row0 + 16*R + 4*q;
        float4 o;
        o.x = acc[R*4+C][0]; o.y = acc[R*4+C][1];
        o.z = acc[R*4+C][2]; o.w = acc[R*4+C][3];
        *(float4*)&Rpart[((size_t)ch*BT + bt0 + c)*128 + r0] = o;
      }
  } else {
    const float* bp = (m==1)? bp1 : bp2;
    #pragma unroll
    for (int R = 0; R < 2; R++){
      int r0 = row0 + 16*R + 4*q;
      float4 bv = *(const float4*)&bp[r0];
      #pragma unroll
      for (int C = 0; C < 4; C++){
        int c = col0 + 16*C + gma;
        float4v a = acc[R*4+C];
        float4 o;
        o.x = fmaxf(a[0]+bv.x, 0.f); o.y = fmaxf(a[1]+bv.y, 0.f);
        o.z = fmaxf(a[2]+bv.z, 0.f); o.w = fmaxf(a[3]+bv.w, 0.f);
        *(float4*)&Reps[(size_t)(bt0 + c)*384 + m*128 + r0] = o;
      }
    }
  }
}

// ---- mix: m=0 partial reduce + norms/softmax/phase, emit ps hi/lo bf16 ----
__global__ __launch_bounds__(128) void k_mix(const float* Rpart, const float* Reps,
    const float* bp0, const float* smask,
    const float* freq, const float* phem, ushort_t* PsH, ushort_t* PsL, float* Wgt)
{
  __shared__ float part[2][3];
  int bt = blockIdx.x; int t = bt % DT;
  int d = threadIdx.x;
  float r0v = bp0[d];
  #pragma unroll
  for (int ch = 0; ch < 6; ch++)
    r0v += Rpart[((size_t)ch*BT + bt)*128 + d];
  r0v = fmaxf(r0v, 0.f);
  float r1v = Reps[(size_t)bt*384 + 128 + d];
  float r2v = Reps[(size_t)bt*384 + 256 + d];
  float s0 = r0v*r0v, s1 = r1v*r1v, s2 = r2v*r2v;
  #pragma unroll
  for (int off = 1; off < 64; off <<= 1){
    s0 += __shfl_xor(s0, off, 64);
    s1 += __shfl_xor(s1, off, 64);
    s2 += __shfl_xor(s2, off, 64);
  }
  int wv = d >> 6;
  if ((d & 63) == 0){ part[wv][0] = s0; part[wv][1] = s1; part[wv][2] = s2; }
  __syncthreads();
  float n0 = sqrtf(part[0][0] + part[1][0]);
  float n1 = sqrtf(part[0][1] + part[1][1]);
  float n2 = sqrtf(part[0][2] + part[1][2]);
  float mx = fmaxf(n0, fmaxf(n1, n2));
  float e0 = expf(n0-mx), e1 = expf(n1-mx), e2 = expf(n2-mx);
  float einv = 1.f/(e0+e1+e2);
  if (d < 3) Wgt[bt*3+d] = (d==0?e0:(d==1?e1:e2))*einv;
  float sm0 = smask[bt*2], sm1 = smask[bt*2+1];
  int id = (sm1 > sm0) ? 1 : 0;
  float ph = (float)t * freq[id*DD+d] + phem[id*DD+d];
  float cp = cosf(ph), sp = sinf(ph);
  float a0 = r0v / fmaxf(n0, 1e-12f);
  float a1 = r1v / fmaxf(n1, 1e-12f);
  float a2 = r2v / fmaxf(n2, 1e-12f);
  ushort_t h, l;
  split2(a0*cp, h, l); PsH[((size_t)0*BT + bt)*DD + d] = h; PsL[((size_t)0*BT + bt)*DD + d] = l;
  split2(a1*cp, h, l); PsH[((size_t)1*BT + bt)*DD + d] = h; PsL[((size_t)1*BT + bt)*DD + d] = l;
  split2(a2*cp, h, l); PsH[((size_t)2*BT + bt)*DD + d] = h; PsL[((size_t)2*BT + bt)*DD + d] = l;
  split2(a0*sp, h, l); PsH[((size_t)3*BT + bt)*DD + d] = h; PsL[((size_t)3*BT + bt)*DD + d] = l;
  split2(a1*sp, h, l); PsH[((size_t)4*BT + bt)*DD + d] = h; PsL[((size_t)4*BT + bt)*DD + d] = l;
  split2(a2*sp, h, l); PsH[((size_t)5*BT + bt)*DD + d] = h; PsL[((size_t)5*BT + bt)*DD + d] = l;
}

// ---- qtrans v2: Q = ps @ Ux^T, + pow2 s=2 piggyback ----
__global__ __launch_bounds__(512,1) void k_qtrans(const ushort_t* UxH, const ushort_t* UxL,
                                                  const ushort_t* PsH, const ushort_t* PsL,
                                                  ushort_t* Qb,
                                                  ushort_t* PpH, ushort_t* PpL,
                                                  ushort_t* PTh, ushort_t* PTl){
  __shared__ ushort_t Ah[128*SP], Al[128*SP], Bh[128*SP], Bl[128*SP];
  int blk = blockIdx.x;
  int tid = threadIdx.x;
  if (blk >= 90){
    pow2_body(blk - 90, 2, PpH, PpL, PTh, PTl, tid, Ah, Al, Bh, Bl);
    return;
  }
  int w = tid >> 6, lane = tid & 63, gma = lane & 15, q = lane >> 4;
  int row0 = 32*(w >> 1), col0 = 64*(w & 1);
  size_t rbase = (size_t)blk*128*128;
  lds_load_mat<512>(Ah, UxH, tid);
  lds_load_mat<512>(Al, UxL, tid);
  lds_load_mat<512>(Bh, PsH + rbase, tid);
  lds_load_mat<512>(Bl, PsL + rbase, tid);
  __syncthreads();
  float4v acc[8];
  #pragma unroll
  for (int i = 0; i < 8; i++) acc[i] = (float4v){0.f,0.f,0.f,0.f};
  gemm_t<2,4,true,true>(Ah, Al, Bh, Bl, acc, row0, col0, gma, q);
  emit_t<2,4>(acc, Qb + rbase, 128, row0, col0, gma, q);
}

// ---- powgchain (COOPERATIVE, 60 blk x 512): s=3,4,5 on blocks 0-15 with
// grid.sync between, then gchain on all 60 blocks. ----
__global__ __launch_bounds__(512,1) void k_powgchain(
    ushort_t* PpH, ushort_t* PpL, ushort_t* PTh, ushort_t* PTl,
    ushort_t* GTh, ushort_t* GTl)
{
  __shared__ ushort_t Ah[128*SP], Al[128*SP], Bh[128*SP], Bl[128*SP];
  cg::grid_group grid = cg::this_grid();
  int t = blockIdx.x;
  int tid = threadIdx.x;
  for (int s = 3; s <= 5; s++){
    if (t < 16) pow2_body(t, s, PpH, PpL, PTh, PTl, tid, Ah, Al, Bh, Bl);
    grid.sync();
  }
  int w = tid >> 6, lane = tid & 63, gma = lane & 15, q = lane >> 4;
  int row0 = 32*(w >> 1), col0 = 64*(w & 1);
  size_t gslot = (size_t)t * 16384;
  if (t == 0){
    for (int i = tid*4; i < 16384; i += 2048){
      int r = i >> 7, k = i & 127;
      ushort4 zz; zz.x = zz.y = zz.z = zz.w = 0;
      *(ushort4*)&GTl[gslot + i] = zz;
      ushort4 oh;
      oh.x = (r == (k+0)) ? (ushort_t)0x3F80 : (ushort_t)0;
      oh.y = (r == (k+1)) ? (ushort_t)0x3F80 : (ushort_t)0;
      oh.z = (r == (k+2)) ? (ushort_t)0x3F80 : (ushort_t)0;
      oh.w = (r == (k+3)) ? (ushort_t)0x3F80 : (ushort_t)0;
      *(ushort4*)&GTh[gslot + i] = oh;
    }
    return;
  }
  int b0 = __ffs(t) - 1;
  int rem = t & ~(1 << b0);
  if (rem == 0){
    size_t ps = (size_t)b0 * 16384;
    for (int i = tid*4; i < 16384; i += 2048){
      *(ushort4*)&GTh[gslot + i] = *(const ushort4*)&PTh[ps + i];
      *(ushort4*)&GTl[gslot + i] = *(const ushort4*)&PTl[ps + i];
    }
    return;
  }
  lds_load_mat<512>(Ah, PpH + (size_t)b0*16384, tid);
  lds_load_mat<512>(Al, PpL + (size_t)b0*16384, tid);
  while (rem){
    int k = __ffs(rem) - 1;
    rem &= ~(1 << k);
    lds_load_mat<512>(Bh, PTh + (size_t)k*16384, tid);
    lds_load_mat<512>(Bl, PTl + (size_t)k*16384, tid);
    __syncthreads();
    float4v acc[8];
    #pragma unroll
    for (int i = 0; i < 8; i++) acc[i] = (float4v){0.f,0.f,0.f,0.f};
    if (rem){
      gemm_t<2,4,true,true>(Bh, Bl, Ah, Al, acc, row0, col0, gma, q);
      __syncthreads();
      emit_split_t<2,4>(acc, Ah, Al, SP, row0, col0, gma, q);
      __syncthreads();
    } else {
      gemm_t<2,4,true,true>(Ah, Al, Bh, Bl, acc, row0, col0, gma, q);
      emit_split_t<2,4>(acc, GTh + gslot, GTl + gslot, 128, row0, col0, gma, q);
    }
  }
}

// ---- mwvt: precompMW (blk<180, tid<256 guarded) + vtrans (blk>=180) ----
__global__ __launch_bounds__(512,1) void k_mwvt(
    const ushort_t* GTh, const ushort_t* GTl,
    const ushort_t* UxTh, const ushort_t* UxTl,
    const float* Vr, const float* Vi,
    const ushort_t* Qb,
    ushort_t* Mh, ushort_t* Wh, ushort_t* At)
{
  __shared__ ushort_t LBUF[4*128*SP];
  int blk = blockIdx.x;
  int tid = threadIdx.x;
  if (blk < 180){
    ushort_t* Bh = LBUF;
    ushort_t* Bl = LBUF + 128*SP;
    ushort_t* Ah = LBUF + 2*128*SP;
    ushort_t* Al = LBUF + 3*128*SP;
    int w = tid >> 6, lane = tid & 63, gma = lane & 15, q = lane >> 4;
    int row0 = 64*(w >> 1), col0 = 64*(w & 1);
    if (blk < 60){
      int t = blk;
      if (tid < 256){
        lds_load_mat<256>(Bh, GTh + (size_t)t*16384, tid);
        lds_load_mat<256>(Bl, GTl + (size_t)t*16384, tid);
        lds_load_mat<256>(Ah, UxTh, tid);
        lds_load_mat<256>(Al, UxTl, tid);
      }
      __syncthreads();
      float4v acc[16];
      if (tid < 256){
        #pragma unroll
        for (int i = 0; i < 16; i++) acc[i] = (float4v){0.f,0.f,0.f,0.f};
        gemm_t<4,4,true,true>(Ah, Al, Bh, Bl, acc, row0, col0, gma, q);
      }
      __syncthreads();
      if (tid < 256) emit_split_t<4,4>(acc, Ah, Al, SP, row0, col0, gma, q);
      __syncthreads();
      if (tid < 256){
        #pragma unroll
        for (int i = 0; i < 16; i++) acc[i] = (float4v){0.f,0.f,0.f,0.f};
        gemm_t<4,4,true,true>(Bh, Bl, Ah, Al, acc, row0, col0, gma, q);
        #pragma unroll
        for (int R = 0; R < 4; R++)
          #pragma unroll
          for (int C = 0; C < 4; C++){
            int c = col0 + 16*C + gma, r0 = row0 + 16*R + 4*q;
            uint2 o;
            o.x = f2bfpk(acc[R*4+C][0], acc[R*4+C][1]);
            o.y = f2bfpk(acc[R*4+C][2], acc[R*4+C][3]);
            *(uint2*)&Mh[(size_t)t*16384 + c*128 + r0] = o;
          }
      }
    } else {
      int bx = blk - 60;
      int t = bx >> 1, which = bx & 1;
      if (tid < 256){
        lds_load_mat<256>(Ah, GTh + (size_t)t*16384, tid);
        lds_load_mat<256>(Al, GTl + (size_t)t*16384, tid);
        const float* V = which ? Vi : Vr;
        for (int i = tid; i < 16384; i += 256){
          int r = i >> 7, k = i & 127;
          ushort_t h, l; split2(V[i], h, l);
          Bh[r*SP + k] = h; Bl[r*SP + k] = l;
        }
      }
      __syncthreads();
      if (tid < 256){
        float4v acc[16];
        #pragma unroll
        for (int i = 0; i < 16; i++) acc[i] = (float4v){0.f,0.f,0.f,0.f};
        gemm_t<4,4,true,true>(Ah, Al, Bh, Bl, acc, row0, col0, gma, q);
        #pragma unroll
        for (int R = 0; R < 4; R++)
          #pragma unroll
          for (int C = 0; C < 4; C++){
            int c = col0 + 16*C + gma, r0 = row0 + 16*R + 4*q;
            uint2 o;
            o.x = f2bfpk(acc[R*4+C][0], acc[R*4+C][1]);
            o.y = f2bfpk(acc[R*4+C][2], acc[R*4+C][3]);
            *(uint2*)&Wh[(size_t)bx*16384 + c*128 + r0] = o;
          }
      }
    }
  } else {
    // vtrans: per t, A'[j,b] = G_t^T q_{j,b}
    ushort_t* Ah = LBUF;                 // 128*SP
    ushort_t* Bs = LBUF + 128*SP;        // 192*SP (fits in remaining 3*128*SP)
    int t = blk - 180;
    int w = tid >> 6, lane = tid & 63, gma = lane & 15, q = lane >> 4;
    int row0 = (w & 3)*32, col0 = (w >> 2)*96;
    lds_load_mat<512>(Ah, GTh + (size_t)t*16384, tid);
    for (int i = tid*8; i < 192*128; i += 4096){
      int m = i >> 7, k = i & 127;
      int j = m >> 5, b = m & 31;
      *(ushort8_t*)&Bs[m*SP + k] =
        *(const ushort8_t*)&Qb[((size_t)(j*BT) + b*DT + t)*DD + k];
    }
    __syncthreads();
    float4v acc[12];
    #pragma unroll
    for (int i = 0; i < 12; i++) acc[i] = (float4v){0.f,0.f,0.f,0.f};
    gemm_t<2,6,false,false>(Ah, Ah, Bs, Bs, acc, row0, col0, gma, q);
    emit_t<2,6>(acc, At + (size_t)t*24576, 128, row0, col0, gma, q);
  }
}

// ---- zbuild v2: rank-6 Y build + lambda-prefix, latency-hidden ----
__global__ __launch_bounds__(256) void k_zbuild(ushort_t* S, const ushort_t* At,
                                                const float* Wgt, const float* lamp){
  __shared__ ushort_t As[2][6*DD];
  __shared__ float wl[2][3];
  int blk = blockIdx.x;
  int b = blk >> 5, sl2 = blk & 31;
  int tid = threadIdx.x;
  int r = sl2*4 + (tid >> 6);
  int c = (tid*2) & 127;
  float lam = lamp[0];
  float z0 = 0.f, z1 = 0.f;
  size_t off = (size_t)sl2*512 + tid*2;
  ushort4 pre;
  float wpre = 0.f;
  int jj0 = 0, n0 = 0;
  if (tid < 192){
    int i = tid*4;
    jj0 = i >> 7; n0 = i & 127;
    pre = *(const ushort4*)&At[(size_t)(jj0*32 + b)*128 + n0];
  }
  if (tid < 3) wpre = Wgt[(b*DT)*3 + tid];
  for (int t = 0; t < DT; t++){
    int cur = t & 1;
    if (tid < 192) *(ushort4*)&As[cur][tid*4] = pre;
    if (tid < 3) wl[cur][tid] = wpre;
    __syncthreads();
    if (t+1 < DT){
      if (tid < 192)
        pre = *(const ushort4*)&At[(size_t)(t+1)*24576 + (size_t)(jj0*32 + b)*128 + n0];
      if (tid < 3) wpre = Wgt[(b*DT + t+1)*3 + tid];
    }
    float ar[6];
    #pragma unroll
    for (int jj = 0; jj < 6; jj++) ar[jj] = bf2f(As[cur][jj*128 + r]);
    float w0 = wl[cur][0], w1 = wl[cur][1], w2 = wl[cur][2];
    float cb[6];
    cb[0] = w0*(ar[0]+ar[3]); cb[1] = w1*(ar[1]+ar[4]); cb[2] = w2*(ar[2]+ar[5]);
    cb[3] = w0*(ar[3]-ar[0]); cb[4] = w1*(ar[4]-ar[1]); cb[5] = w2*(ar[5]-ar[2]);
    float y0 = 0.f, y1 = 0.f;
    #pragma unroll
    for (int jj = 0; jj < 6; jj++){
      unsigned int a2 = *(const unsigned int*)&As[cur][jj*128 + c];
      float w_ = cb[jj];
      y0 += w_*bf2f((ushort_t)(a2 & 0xFFFF));
      y1 += w_*bf2f((ushort_t)(a2 >> 16));
    }
    z0 = lam*z0 + y0; z1 = lam*z1 + y1;
    *(unsigned int*)&S[((size_t)(t*32 + b))*16384 + off] = f2bfpk(z0, z1);
  }
}

// ---- conjmid v2 (512 thr, per (t, 4-b group)): M staged once, 4 b's ----
__global__ __launch_bounds__(512,2) void k_conjmid(ushort_t* S, const ushort_t* Mh,
                                                   const float* lamp){
  __shared__ ushort_t Bh[128*SP], Zs[128*SP];
  int raw = blockIdx.x;            // 480 = 60 t x 8 g
  int g = raw & 7, t = raw >> 3;
  int tid = threadIdx.x;
  int w = tid >> 6, lane = tid & 63, gma = lane & 15, q = lane >> 4;
  int row0 = 32*(w >> 1), col0 = 64*(w & 1);
  size_t slot0 = (size_t)(t*32 + g*4) * 16384;
  lds_load_mat2<512>(Zs, S + slot0, Bh, Mh + (size_t)t*16384, tid);
  __syncthreads();
  float lam = lamp[0];
  float oml = 1.f - lam;
  float ct = powf(lam, (float)(t+1)) / 128.f;
  for (int ib = 0; ib < 4; ib++){
    size_t slot = slot0 + (size_t)ib*16384;
    ushort8_t znext[4];
    if (ib < 3){
      #pragma unroll
      for (int c = 0; c < 4; c++)
        znext[c] = *(const ushort8_t*)&S[slot + 16384 + tid*8 + c*4096];
    }
    float4v acc[8];
    #pragma unroll
    for (int i = 0; i < 8; i++) acc[i] = (float4v){0.f,0.f,0.f,0.f};
    gemm_t<2,4,false,false>(Zs, Zs, Bh, Bh, acc, row0, col0, gma, q);
    __syncthreads();
    emit_t<2,4>(acc, Zs, SP, row0, col0, gma, q);
    __syncthreads();
    #pragma unroll
    for (int i = 0; i < 8; i++) acc[i] = (float4v){0.f,0.f,0.f,0.f};
    gemm_t<2,4,false,false>(Zs, Zs, Bh, Bh, acc, row0, col0, gma, q);
    __syncthreads();
    #pragma unroll
    for (int R = 0; R < 2; R++)
      #pragma unroll
      for (int C = 0; C < 4; C++){
        int c = col0 + 16*C + gma, r0 = row0 + 16*R + 4*q;
        float v0 = oml*acc[R*4+C][0] + ((c == r0+0) ? ct : 0.f);
        float v1 = oml*acc[R*4+C][1] + ((c == r0+1) ? ct : 0.f);
        float v2 = oml*acc[R*4+C][2] + ((c == r0+2) ? ct : 0.f);
        float v3 = oml*acc[R*4+C][3] + ((c == r0+3) ? ct : 0.f);
        uint2 o; o.x = f2bfpk(v0, v1); o.y = f2bfpk(v2, v3);
        *(uint2*)&Zs[(size_t)c*SP + r0] = o;
      }
    __syncthreads();
    lds_store_mat<512>(S + slot, Zs, tid);
    if (ib < 3){
      __syncthreads();
      #pragma unroll
      for (int c = 0; c < 4; c++){
        int i = tid*8 + c*4096;
        int r = i >> 7, k = i & 127;
        *(ushort8_t*)&Zs[r*SP + k] = znext[c];
      }
      __syncthreads();
    }
  }
}

// ---- prefix v3: 1024 blk (32 chains x 32 slabs), 8B/lane, depth-6 ----
__device__ __forceinline__ void prefix_ph2(uint2& buf, bool doload,
                                           const ushort_t* Snext, ushort_t* Scur,
                                           float* a, float lam){
  uint2 u = buf;
  if (doload) buf = *(const uint2*)Snext;
  a[0] = lam*a[0] + bf2f((ushort_t)(u.x & 0xFFFF));
  a[1] = lam*a[1] + bf2f((ushort_t)(u.x >> 16));
  a[2] = lam*a[2] + bf2f((ushort_t)(u.y & 0xFFFF));
  a[3] = lam*a[3] + bf2f((ushort_t)(u.y >> 16));
  uint2 o;
  o.x = f2bfpk(a[0], a[1]); o.y = f2bfpk(a[2], a[3]);
  *(uint2*)Scur = o;
}
__global__ __launch_bounds__(128) void k_prefix(ushort_t* S, const float* lamp){
  int blk = blockIdx.x;            // 1024 = 32 chains x 32 slabs
  int chain = blk >> 5, slab = blk & 31;
  int tid = threadIdx.x;
  size_t off = (size_t)slab*512 + tid*4;
  float lam = lamp[0];
  float a[4];
  #pragma unroll
  for (int i = 0; i < 4; i++) a[i] = 0.f;
  size_t addr = (size_t)chain*16384 + off;
  const size_t step = (size_t)32*16384;
  uint2 b0 = *(const uint2*)&S[addr];
  uint2 b1 = *(const uint2*)&S[addr + step];
  uint2 b2 = *(const uint2*)&S[addr + 2*step];
  uint2 b3 = *(const uint2*)&S[addr + 3*step];
  uint2 b4 = *(const uint2*)&S[addr + 4*step];
  uint2 b5 = *(const uint2*)&S[addr + 5*step];
  for (int t = 0; t < DT; t += 6){
    prefix_ph2(b0, t+6  < DT, &S[addr + 6*step], &S[addr], a, lam); addr += step;
    prefix_ph2(b1, t+7  < DT, &S[addr + 6*step], &S[addr], a, lam); addr += step;
    prefix_ph2(b2, t+8  < DT, &S[addr + 6*step], &S[addr], a, lam); addr += step;
    prefix_ph2(b3, t+9  < DT, &S[addr + 6*step], &S[addr], a, lam); addr += step;
    prefix_ph2(b4, t+10 < DT, &S[addr + 6*step], &S[addr], a, lam); addr += step;
    prefix_ph2(b5, t+11 < DT, &S[addr + 6*step], &S[addr], a, lam); addr += step;
  }
}

// ---- meas v7 (512 thr, per (t,h,8-b group)): V staged ONCE, loop 8 b's;
// raw = h*240 + t*4 + g so h-siblings share XCD (240 % 8 == 0). ----
__global__ __launch_bounds__(512,2) void k_meas(const ushort_t* S, const ushort_t* Wh,
                                                const float* lamp, float* Probs){
  __shared__ ushort_t Vs[128*SP], Cs[128*SP];
  __shared__ float Pd[64];
  int raw = blockIdx.x;            // 480 = 2 h x (60 t x 4 g)
  int h = raw / 240;
  int rem = raw % 240;
  int t = rem >> 2, g = rem & 3;
  int tid = threadIdx.x;
  int w = tid >> 6, lane = tid & 63, gma = lane & 15, q = lane >> 4;
  int row0 = 16*(w >> 1);
  int col0 = 64*(w & 1);
  size_t wbase = (size_t)(t*2) * 16384;
  size_t slot0 = (size_t)(t*32 + g*8) * 16384;
  ushort8_t creg[4], vreg[4];
  #pragma unroll
  for (int c = 0; c < 4; c++)
    creg[c] = *(const ushort8_t*)&S[slot0 + tid*8 + c*4096];
  #pragma unroll
  for (int c = 0; c < 4; c++){
    int i = tid*8 + c*4096;
    int r = i >> 7, k = i & 127;
    size_t gsrc = wbase + ((r < 64) ? 0 : 16384) + (size_t)(64*h + (r & 63))*128 + k;
    vreg[c] = *(const ushort8_t*)&Wh[gsrc];
  }
  if (tid < 64) Pd[tid] = 0.f;
  #pragma unroll
  for (int c = 0; c < 4; c++){
    int i = tid*8 + c*4096;
    int r = i >> 7, k = i & 127;
    *(ushort8_t*)&Cs[r*SP + k] = creg[c];
    *(ushort8_t*)&Vs[r*SP + k] = vreg[c];
  }
  __syncthreads();
  float lam = lamp[0];
  float ct = powf(lam, (float)(t+1)) / 128.f;
  for (int ib = 0; ib < 8; ib++){
    if (ib < 7){
      size_t snx = slot0 + (size_t)(ib+1)*16384;
      #pragma unroll
      for (int c = 0; c < 4; c++)
        creg[c] = *(const ushort8_t*)&S[snx + tid*8 + c*4096];
    }
    float4v acc[8];
    #pragma unroll
    for (int i = 0; i < 8; i++) acc[i] = (float4v){0.f,0.f,0.f,0.f};
    #pragma unroll
    for (int ks = 0; ks < 4; ks++){
      int ko = ks*32 + q*8;
      bf16x8 aF0 = *(const bf16x8*)&Vs[(row0 + gma)*SP + ko];
      bf16x8 aF1 = *(const bf16x8*)&Vs[(row0 + 64 + gma)*SP + ko];
      bf16x8 bF[4];
      #pragma unroll
      for (int C = 0; C < 4; C++)
        bF[C] = *(const bf16x8*)&Cs[(col0 + 16*C + gma)*SP + ko];
      #pragma unroll
      for (int C = 0; C < 4; C++){
        acc[C]   = __builtin_amdgcn_mfma_f32_16x16x32_bf16(aF0, bF[C], acc[C],   0, 0, 0);
        acc[4+C] = __builtin_amdgcn_mfma_f32_16x16x32_bf16(aF1, bF[C], acc[4+C], 0, 0, 0);
      }
    }
    #pragma unroll
    for (int j = 0; j < 4; j++){
      int kr = row0 + 4*q + j;
      float s = 0.f;
      #pragma unroll
      for (int C = 0; C < 4; C++){
        int m = col0 + 16*C + gma;
        float w0 = bf2f(Vs[kr*SP + m]);
        float w1 = bf2f(Vs[(kr + 64)*SP + m]);
        s += acc[C][j]*(w0 + w1) + acc[4+C][j]*(w1 - w0);
      }
      #pragma unroll
      for (int off = 1; off < 16; off <<= 1)
        s += __shfl_xor(s, off, 64);
      if (gma == 0) atomicAdd(&Pd[kr], s);
    }
    __syncthreads();
    if (tid < 64){
      Probs[(size_t)(t*32 + g*8 + ib)*DD + 64*h + tid] = (1.f - lam)*Pd[tid] + ct;
      Pd[tid] = 0.f;
    }
    if (ib < 7){
      #pragma unroll
      for (int c = 0; c < 4; c++){
        int i = tid*8 + c*4096;
        int r = i >> 7, k = i & 127;
        *(ushort8_t*)&Cs[r*SP + k] = creg[c];
      }
    }
    __syncthreads();
  }
}

// ---- head ----
__global__ __launch_bounds__(64) void k_head(const float* Probs, const float* W1, const float* b1,
                        const float* W2, const float* b2, float* out)
{
  __shared__ float ps[DD];
  __shared__ float hid[64];
  __shared__ float ov[4];
  int tb = blockIdx.x;
  int tid = threadIdx.x;
  ps[tid] = Probs[(size_t)tb*DD + tid];
  ps[tid+64] = Probs[(size_t)tb*DD + 64 + tid];
  __syncthreads();
  float acc = b1[tid];
  for (int dd = 0; dd < DD; dd++) acc += ps[dd]*W1[dd*64 + tid];
  hid[tid] = fmaxf(acc, 0.f);
  __syncthreads();
  if (tid < 4){
    float o = b2[tid];
    for (int j = 0; j < 64; j++) o += hid[j]*W2[j*4 + tid];
    ov[tid] = tanhf(o);
  }
  __syncthreads();
  if (tid == 0){
    float m = fmaxf(fmaxf(ov[0],ov[1]), fmaxf(ov[2],ov[3]));
    float lse = logf(expf(ov[0]-m)+expf(ov[1]-m)+expf(ov[2]-m)+expf(ov[3]-m));
    int t = tb >> 5, b = tb & 31;
    float* o = out + ((size_t)(b*DT + t))*4;
    o[0] = ov[0]-m-lse; o[1] = ov[1]-m-lse;
    o[2] = ov[2]-m-lse; o[3] = ov[3]-m-lse;
  }
}

extern "C" void kernel_launch(void* const* d_in, const int* in_sizes, int n_in,
                              void* d_out, int out_size, void* d_ws, size_t ws_size,
                              hipStream_t stream)
{
  const float* x0    = (const float*)d_in[0];
  const float* x1    = (const float*)d_in[1];
  const float* x2    = (const float*)d_in[2];
  const float* smask = (const float*)d_in[3];
  const float* Wp0   = (const float*)d_in[4];
  const float* bp0   = (const float*)d_in[5];
  const float* Wp1   = (const float*)d_in[6];
  const float* bp1   = (const float*)d_in[7];
  const float* Wp2   = (const float*)d_in[8];
  const float* bp2   = (const float*)d_in[9];
  const float* freq  = (const float*)d_in[10];
  const float* phem  = (const float*)d_in[11];
  const float* Ux    = (const float*)d_in[12];
  const float* Uh    = (const float*)d_in[13];
  const float* lamp  = (const float*)d_in[14];
  const float* kr    = (const float*)d_in[15];
  const float* ki    = (const float*)d_in[16];
  const float* W1    = (const float*)d_in[17];
  const float* b1    = (const float*)d_in[18];
  const float* W2    = (const float*)d_in[19];
  const float* b2    = (const float*)d_in[20];

  char* ws = (char*)d_ws;
  auto alignup = [](size_t x){ return (x + 255) & ~(size_t)255; };
  size_t off = 0;
  ushort_t* S   = (ushort_t*)(ws + off); off = alignup(off + (size_t)1920*16384*sizeof(ushort_t));
  ushort_t* Qb  = (ushort_t*)(ws + off); off = alignup(off + (size_t)6*BT*DD*sizeof(ushort_t));
  float* Rpart  = (float*)(ws + off);    off = alignup(off + (size_t)6*BT*DD*sizeof(float));
  float* Reps   = (float*)(ws + off);    off = alignup(off + (size_t)BT*384*sizeof(float));
  ushort_t* PsH = (ushort_t*)(ws + off); off = alignup(off + (size_t)6*BT*DD*sizeof(ushort_t));
  ushort_t* PsL = (ushort_t*)(ws + off); off = alignup(off + (size_t)6*BT*DD*sizeof(ushort_t));
  ushort_t* X0h = (ushort_t*)(ws + off); off = alignup(off + (size_t)BT*768*sizeof(ushort_t));
  ushort_t* X0l = (ushort_t*)(ws + off); off = alignup(off + (size_t)BT*768*sizeof(ushort_t));
  ushort_t* X1h = (ushort_t*)(ws + off); off = alignup(off + (size_t)BT*128*sizeof(ushort_t));
  ushort_t* X1l = (ushort_t*)(ws + off); off = alignup(off + (size_t)BT*128*sizeof(ushort_t));
  ushort_t* X2h = (ushort_t*)(ws + off); off = alignup(off + (size_t)BT*128*sizeof(ushort_t));
  ushort_t* X2l = (ushort_t*)(ws + off); off = alignup(off + (size_t)BT*128*sizeof(ushort_t));
  float* Wgt    = (float*)(ws + off);    off = alignup(off + (size_t)BT*3*sizeof(float));
  float* Vr     = (float*)(ws + off);    off = alignup(off + (size_t)DD*DD*sizeof(float));
  float* Vi     = (float*)(ws + off);    off = alignup(off + (size_t)DD*DD*sizeof(float));
  ushort_t* UxTh = (ushort_t*)(ws + off); off = alignup(off + (size_t)DD*DD*sizeof(ushort_t));
  ushort_t* UxTl = (ushort_t*)(ws + off); off = alignup(off + (size_t)DD*DD*sizeof(ushort_t));
  ushort_t* UxH = (ushort_t*)(ws + off); off = alignup(off + (size_t)DD*DD*sizeof(ushort_t));
  ushort_t* UxL = (ushort_t*)(ws + off); off = alignup(off + (size_t)DD*DD*sizeof(ushort_t));
  float* Probs  = (float*)(ws + off);    off = alignup(off + (size_t)BT*DD*sizeof(float));
  ushort_t* PpH = (ushort_t*)(ws + off); off = alignup(off + (size_t)6*16384*sizeof(ushort_t));
  ushort_t* PpL = (ushort_t*)(ws + off); off = alignup(off + (size_t)6*16384*sizeof(ushort_t));
  ushort_t* PTh = (ushort_t*)(ws + off); off = alignup(off + (size_t)6*16384*sizeof(ushort_t));
  ushort_t* PTl = (ushort_t*)(ws + off); off = alignup(off + (size_t)6*16384*sizeof(ushort_t));
  ushort_t* Mh  = (ushort_t*)(ws + off); off = alignup(off + (size_t)60*16384*sizeof(ushort_t));
  ushort_t* Wmh = (ushort_t*)(ws + off); off = alignup(off + (size_t)120*16384*sizeof(ushort_t));
  ushort_t* GTh = (ushort_t*)(ws + off); off = alignup(off + (size_t)60*16384*sizeof(ushort_t));
  ushort_t* GTl = (ushort_t*)(ws + off); off = alignup(off + (size_t)60*16384*sizeof(ushort_t));
  ushort_t* At  = (ushort_t*)(ws + off); off = alignup(off + (size_t)60*24576*sizeof(ushort_t));
  ushort_t* WT0h = (ushort_t*)(ws + off); off = alignup(off + (size_t)128*768*sizeof(ushort_t));
  ushort_t* WT0l = (ushort_t*)(ws + off); off = alignup(off + (size_t)128*768*sizeof(ushort_t));
  ushort_t* WT1h = (ushort_t*)(ws + off); off = alignup(off + (size_t)128*128*sizeof(ushort_t));
  ushort_t* WT1l = (ushort_t*)(ws + off); off = alignup(off + (size_t)128*128*sizeof(ushort_t));
  ushort_t* WT2h = (ushort_t*)(ws + off); off = alignup(off + (size_t)128*128*sizeof(ushort_t));
  ushort_t* WT2l = (ushort_t*)(ws + off); off = alignup(off + (size_t)128*128*sizeof(ushort_t));
  (void)ws_size; (void)in_sizes; (void)n_in; (void)out_size;

  k_small<<<512 + BT, 128, 0, stream>>>(Ux, Uh, kr, ki, Wp0, Wp1, Wp2, x0, x1, x2,
                                        UxTh, UxTl, UxH, UxL, Vr, Vi,
                                        PpH, PpL, PTh, PTl,
                                        WT0h, WT0l, WT1h, WT1l, WT2h, WT2l,
                                        X0h, X0l, X1h, X1l, X2h, X2l);
  k_proj<<<136, 512, 0, stream>>>(X0h, X0l, X1h, X1l, X2h, X2l,
                                  WT0h, WT0l, WT1h, WT1l, WT2h, WT2l,
                                  bp1, bp2, Rpart, Reps, PpH, PpL, PTh, PTl);
  k_mix<<<BT, 128, 0, stream>>>(Rpart, Reps, bp0, smask, freq, phem, PsH, PsL, Wgt);
  k_qtrans<<<106, 512, 0, stream>>>(UxH, UxL, PsH, PsL, Qb, PpH, PpL, PTh, PTl);
  {
    void* cargs[] = {(void*)&PpH, (void*)&PpL, (void*)&PTh, (void*)&PTl,
                     (void*)&GTh, (void*)&GTl};
    hipLaunchCooperativeKernel((const void*)k_powgchain, dim3(60), dim3(512),
                               cargs, 0, stream);
  }
  k_mwvt<<<240, 512, 0, stream>>>(GTh, GTl, UxTh, UxTl, Vr, Vi, Qb, Mh, Wmh, At);
  k_zbuild<<<1024, 256, 0, stream>>>(S, At, Wgt, lamp);
  k_conjmid<<<480, 512, 0, stream>>>(S, Mh, lamp);
  k_prefix<<<1024, 128, 0, stream>>>(S, lamp);
  k_meas<<<480, 512, 0, stream>>>(S, Wmh, lamp, Probs);
  k_head<<<BT, 64, 0, stream>>>(Probs, W1, b1, W2, b2, (float*)d_out);
}

// Round 15
// 294.172 us; speedup vs baseline: 1.1969x; 1.1969x over previous
//
#include <hip/hip_runtime.h>

// QMN B=32,T=60,D=128. Round 25: revert cooperative powgchain (54us,
// grid.sync ~15us/each on MI355X -- far costlier than a launch boundary).
// Back to r23's pow2v2 s3..5 + gchain launches; KEEP k_meas v7 (NB=8).

#define DB 32
#define DT 60
#define DD 128
#define BT (DB*DT)
#define SP 136

typedef unsigned short ushort_t;
typedef __attribute__((ext_vector_type(8))) __bf16 bf16x8;
typedef __attribute__((ext_vector_type(8))) unsigned short ushort8_t;
typedef __attribute__((ext_vector_type(4))) float  float4v;

__device__ __forceinline__ float bf2f(ushort_t u){
  union { unsigned int i; float f; } x; x.i = ((unsigned int)u) << 16; return x.f;
}
__device__ __forceinline__ ushort_t f2bf(float f){
  union { float f; unsigned int i; } x; x.f = f;
  unsigned int lsb = (x.i >> 16) & 1u;
  return (ushort_t)((x.i + 0x7FFFu + lsb) >> 16);
}
__device__ __forceinline__ unsigned int f2bfpk(float a, float b){
#if defined(__gfx950__) && __has_builtin(__builtin_amdgcn_cvt_pk_bf16_f32)
  auto v = __builtin_amdgcn_cvt_pk_bf16_f32(a, b);
  unsigned int r; __builtin_memcpy(&r, &v, 4); return r;
#else
  return (unsigned int)f2bf(a) | ((unsigned int)f2bf(b) << 16);
#endif
}
__device__ __forceinline__ void split2(float v, ushort_t& h, ushort_t& l){
  h = f2bf(v); l = f2bf(v - bf2f(h));
}

// D[m][n] = sum_k A[m][k]*B[n][k]
template<int RT, int CT, bool ALO, bool BLO>
__device__ __forceinline__ void gemm_t(const ushort_t* Ah, const ushort_t* Al,
                                       const ushort_t* Bh, const ushort_t* Bl,
                                       float4v* acc, int row0, int col0, int gma, int q)
{
  for (int ks = 0; ks < 4; ks++){
    int ko = ks*32 + q*8;
    bf16x8 aF[RT], aL[RT], bF[CT], bL[CT];
    #pragma unroll
    for (int R = 0; R < RT; R++){
      int row = row0 + 16*R + gma;
      aF[R] = *(const bf16x8*)&Ah[row*SP + ko];
      if (ALO) aL[R] = *(const bf16x8*)&Al[row*SP + ko];
    }
    #pragma unroll
    for (int C = 0; C < CT; C++){
      int row = col0 + 16*C + gma;
      bF[C] = *(const bf16x8*)&Bh[row*SP + ko];
      if (BLO) bL[C] = *(const bf16x8*)&Bl[row*SP + ko];
    }
    #pragma unroll
    for (int R = 0; R < RT; R++)
      #pragma unroll
      for (int C = 0; C < CT; C++){
        float4v c = acc[R*CT+C];
        c = __builtin_amdgcn_mfma_f32_16x16x32_bf16(aF[R], bF[C], c, 0, 0, 0);
        if (BLO) c = __builtin_amdgcn_mfma_f32_16x16x32_bf16(aF[R], bL[C], c, 0, 0, 0);
        if (ALO) c = __builtin_amdgcn_mfma_f32_16x16x32_bf16(aL[R], bF[C], c, 0, 0, 0);
        acc[R*CT+C] = c;
      }
  }
}

// transposed store computed(m,n) -> dst[n*stride + m]
template<int RT, int CT>
__device__ __forceinline__ void emit_t(const float4v* acc, ushort_t* dst, int stride,
                                       int row0, int col0, int gma, int q){
  #pragma unroll
  for (int R = 0; R < RT; R++)
    #pragma unroll
    for (int C = 0; C < CT; C++){
      int c = col0 + 16*C + gma, r0 = row0 + 16*R + 4*q;
      uint2 o;
      o.x = f2bfpk(acc[R*CT+C][0], acc[R*CT+C][1]);
      o.y = f2bfpk(acc[R*CT+C][2], acc[R*CT+C][3]);
      *(uint2*)&dst[(size_t)c*stride + r0] = o;
    }
}
template<int RT, int CT>
__device__ __forceinline__ void emit_split_t(const float4v* acc, ushort_t* dh, ushort_t* dl, int stride,
                                             int row0, int col0, int gma, int q){
  #pragma unroll
  for (int R = 0; R < RT; R++)
    #pragma unroll
    for (int C = 0; C < CT; C++){
      int c = col0 + 16*C + gma, r0 = row0 + 16*R + 4*q;
      ushort4 hh, ll;
      split2(acc[R*CT+C][0], hh.x, ll.x); split2(acc[R*CT+C][1], hh.y, ll.y);
      split2(acc[R*CT+C][2], hh.z, ll.z); split2(acc[R*CT+C][3], hh.w, ll.w);
      *(ushort4*)&dh[(size_t)c*stride + r0] = hh;
      *(ushort4*)&dl[(size_t)c*stride + r0] = ll;
    }
}
template<int NT>
__device__ __forceinline__ void lds_load_mat(ushort_t* dst, const ushort_t* src, int tid){
  for (int i = tid*8; i < 16384; i += NT*8){
    int r = i >> 7, k = i & 127;
    *(ushort8_t*)&dst[r*SP + k] = *(const ushort8_t*)&src[i];
  }
}
// 16 rows x 128 cols, contiguous source (2048 elems)
template<int NT>
__device__ __forceinline__ void lds_load_rows16(ushort_t* dst, const ushort_t* src, int tid){
  for (int i = tid*8; i < 2048; i += NT*8){
    int r = i >> 7, k = i & 127;
    *(ushort8_t*)&dst[r*SP + k] = *(const ushort8_t*)&src[i];
  }
}
// issue-early pair stager: all global loads issued, then all ds_writes
template<int NT>
__device__ __forceinline__ void lds_load_mat2(ushort_t* d0, const ushort_t* s0,
                                              ushort_t* d1, const ushort_t* s1, int tid){
  constexpr int CH = 16384/(NT*8);
  ushort8_t r0[CH], r1[CH];
  #pragma unroll
  for (int c = 0; c < CH; c++) r0[c] = *(const ushort8_t*)&s0[tid*8 + c*NT*8];
  #pragma unroll
  for (int c = 0; c < CH; c++) r1[c] = *(const ushort8_t*)&s1[tid*8 + c*NT*8];
  #pragma unroll
  for (int c = 0; c < CH; c++){
    int i = tid*8 + c*NT*8; int r = i >> 7, k = i & 127;
    *(ushort8_t*)&d0[r*SP + k] = r0[c];
  }
  #pragma unroll
  for (int c = 0; c < CH; c++){
    int i = tid*8 + c*NT*8; int r = i >> 7, k = i & 127;
    *(ushort8_t*)&d1[r*SP + k] = r1[c];
  }
}
template<int NT>
__device__ __forceinline__ void lds_store_mat(ushort_t* dst, const ushort_t* src, int tid){
  for (int i = tid*8; i < 16384; i += NT*8){
    int r = i >> 7, k = i & 127;
    *(ushort8_t*)&dst[i] = *(const ushort8_t*)&src[r*SP + k];
  }
}

// ---- pow2 step body (guarded for 512-thr merged launches) ----
__device__ __forceinline__ void pow2_body(int blk2, int s,
    ushort_t* PpH, ushort_t* PpL, ushort_t* PTh, ushort_t* PTl,
    int tid, ushort_t* Ah, ushort_t* Al, ushort_t* Bh, ushort_t* Bl)
{
  int which = blk2 >> 3, sl = blk2 & 7;
  size_t src = (size_t)(s-1)*16384, dst = (size_t)s*16384;
  int gcol0 = sl*16;
  const ushort_t *A_h, *A_l, *B_h, *B_l; ushort_t *D_h, *D_l;
  if (which == 0){ A_h = PTh+src; A_l = PTl+src; B_h = PpH+src; B_l = PpL+src;
                   D_h = PpH+dst; D_l = PpL+dst; }
  else           { A_h = PpH+src; A_l = PpL+src; B_h = PTh+src; B_l = PTl+src;
                   D_h = PTh+dst; D_l = PTl+dst; }
  if (tid < 256){
    lds_load_mat<256>(Ah, A_h, tid);
    lds_load_mat<256>(Al, A_l, tid);
    lds_load_rows16<256>(Bh, B_h + (size_t)gcol0*128, tid);
    lds_load_rows16<256>(Bl, B_l + (size_t)gcol0*128, tid);
  }
  __syncthreads();
  if (tid < 256){
    int w = tid >> 6, lane = tid & 63, gma = lane & 15, q = lane >> 4;
    int row0 = 32*w;
    float4v acc[2];
    acc[0] = (float4v){0.f,0.f,0.f,0.f};
    acc[1] = (float4v){0.f,0.f,0.f,0.f};
    gemm_t<2,1,true,true>(Ah, Al, Bh, Bl, acc, row0, 0, gma, q);
    emit_split_t<2,1>(acc, D_h, D_l, 128, row0, gcol0, gma, q);
  }
}

// ---- small: prepU | normv | initG | weight-transpose prep | xconv ----
__global__ void k_small(const float* Ux, const float* Uh, const float* kr, const float* ki,
                        const float* Wp0, const float* Wp1, const float* Wp2,
                        const float* x0, const float* x1, const float* x2,
                        ushort_t* UxTh, ushort_t* UxTl, ushort_t* UxH, ushort_t* UxL,
                        float* Vr, float* Vi,
                        ushort_t* PpH, ushort_t* PpL, ushort_t* PTh, ushort_t* PTl,
                        ushort_t* WT0h, ushort_t* WT0l, ushort_t* WT1h, ushort_t* WT1l,
                        ushort_t* WT2h, ushort_t* WT2l,
                        ushort_t* X0h, ushort_t* X0l, ushort_t* X1h, ushort_t* X1l,
                        ushort_t* X2h, ushort_t* X2l){
  int blk = blockIdx.x, d = threadIdx.x;
  if (blk < 128){
    int i = blk;
    float v = Ux[i*DD + d];
    ushort_t h, l; split2(v, h, l);
    UxTh[d*DD + i] = h; UxTl[d*DD + i] = l;
  } else if (blk < 256){
    __shared__ float red[DD];
    int k = blk - 128;
    float r = kr[k*DD+d], im = ki[k*DD+d];
    red[d] = r*r + im*im;
    __syncthreads();
    for (int s = 64; s > 0; s >>= 1){ if (d < s) red[d] += red[d+s]; __syncthreads(); }
    float nrm = fmaxf(sqrtf(red[0]), 1e-12f);
    Vr[k*DD+d] = r/nrm; Vi[k*DD+d] = im/nrm;
  } else if (blk < 384){
    int i = blk - 256;
    float v = Uh[i*DD + d];
    ushort_t h, l; split2(v, h, l);
    PpH[i*DD + d] = h;  PpL[i*DD + d] = l;
    PTh[d*DD + i] = h;  PTl[d*DD + i] = l;
  } else if (blk < 512){
    int dd2 = blk - 384;  // output row index d of WT / Ux
    ushort_t h, l;
    for (int k = d; k < 768; k += 128){
      split2(Wp0[(size_t)k*DD + dd2], h, l);
      WT0h[(size_t)dd2*768 + k] = h; WT0l[(size_t)dd2*768 + k] = l;
    }
    { float v = (d < 74) ? Wp1[(size_t)d*DD + dd2] : 0.f;
      split2(v, h, l); WT1h[dd2*128 + d] = h; WT1l[dd2*128 + d] = l; }
    { float v = (d < 35) ? Wp2[(size_t)d*DD + dd2] : 0.f;
      split2(v, h, l); WT2h[dd2*128 + d] = h; WT2l[dd2*128 + d] = l; }
    { split2(Ux[(size_t)dd2*DD + d], h, l);
      UxH[dd2*DD + d] = h; UxL[dd2*DD + d] = l; }
  } else {
    int bt = blk - 512;  // xconv
    ushort_t h, l;
    const float* r0 = x0 + (size_t)bt*768;
    #pragma unroll
    for (int j = 0; j < 6; j++){
      split2(r0[j*128 + d], h, l);
      X0h[(size_t)bt*768 + j*128 + d] = h;
      X0l[(size_t)bt*768 + j*128 + d] = l;
    }
    float v1 = (d < 74) ? x1[(size_t)bt*74 + d] : 0.f;
    split2(v1, h, l);
    X1h[(size_t)bt*128 + d] = h; X1l[(size_t)bt*128 + d] = l;
    float v2 = (d < 35) ? x2[(size_t)bt*35 + d] : 0.f;
    split2(v2, h, l);
    X2h[(size_t)bt*128 + d] = h; X2l[(size_t)bt*128 + d] = l;
  }
}

// ---- proj v3: split-K hi/lo MFMA GEMM, + pow2 s=1 piggyback ----
__global__ __launch_bounds__(512,1) void k_proj(
    const ushort_t* X0h, const ushort_t* X0l, const ushort_t* X1h, const ushort_t* X1l,
    const ushort_t* X2h, const ushort_t* X2l,
    const ushort_t* WT0h, const ushort_t* WT0l, const ushort_t* WT1h, const ushort_t* WT1l,
    const ushort_t* WT2h, const ushort_t* WT2l,
    const float* bp1, const float* bp2,
    float* Rpart, float* Reps,
    ushort_t* PpH, ushort_t* PpL, ushort_t* PTh, ushort_t* PTl)
{
  __shared__ ushort_t Ah[128*SP], Al[128*SP], Bh[128*SP], Bl[128*SP];
  int blk = blockIdx.x;
  int tid = threadIdx.x;
  if (blk >= 120){
    pow2_body(blk - 120, 1, PpH, PpL, PTh, PTl, tid, Ah, Al, Bh, Bl);
    return;
  }
  int m, tile, ch;
  if (blk < 90){ m = 0; tile = blk/6; ch = blk%6; }
  else if (blk < 105){ m = 1; tile = blk-90; ch = 0; }
  else { m = 2; tile = blk-105; ch = 0; }
  int bt0 = tile*128;
  int w = tid >> 6, lane = tid & 63, gma = lane & 15, q = lane >> 4;
  int row0 = 32*(w >> 1), col0 = 64*(w & 1);
  const ushort_t* Wh_ = (m==0)? WT0h : (m==1)? WT1h : WT2h;
  const ushort_t* Wl_ = (m==0)? WT0l : (m==1)? WT1l : WT2l;
  const ushort_t* Xh_ = (m==0)? X0h : (m==1)? X1h : X2h;
  const ushort_t* Xl_ = (m==0)? X0l : (m==1)? X1l : X2l;
  int KX = (m==0)? 768 : 128;
  for (int i = tid*8; i < 16384; i += 4096){
    int r = i >> 7, k = i & 127;
    *(ushort8_t*)&Ah[r*SP + k] = *(const ushort8_t*)&Wh_[(size_t)r*KX + ch*128 + k];
    *(ushort8_t*)&Al[r*SP + k] = *(const ushort8_t*)&Wl_[(size_t)r*KX + ch*128 + k];
    *(ushort8_t*)&Bh[r*SP + k] = *(const ushort8_t*)&Xh_[(size_t)(bt0+r)*KX + ch*128 + k];
    *(ushort8_t*)&Bl[r*SP + k] = *(const ushort8_t*)&Xl_[(size_t)(bt0+r)*KX + ch*128 + k];
  }
  __syncthreads();
  float4v acc[8];
  #pragma unroll
  for (int i = 0; i < 8; i++) acc[i] = (float4v){0.f,0.f,0.f,0.f};
  gemm_t<2,4,true,true>(Ah, Al, Bh, Bl, acc, row0, col0, gma, q);
  if (m == 0){
    #pragma unroll
    for (int R = 0; R < 2; R++)
      #pragma unroll
      for (int C = 0; C < 4; C++){
        int c = col0 + 16*C + gma, r0 = row0 + 16*R + 4*q;
        float4 o;
        o.x = acc[R*4+C][0]; o.y = acc[R*4+C][1];
        o.z = acc[R*4+C][2]; o.w = acc[R*4+C][3];
        *(float4*)&Rpart[((size_t)ch*BT + bt0 + c)*128 + r0] = o;
      }
  } else {
    const float* bp = (m==1)? bp1 : bp2;
    #pragma unroll
    for (int R = 0; R < 2; R++){
      int r0 = row0 + 16*R + 4*q;
      float4 bv = *(const float4*)&bp[r0];
      #pragma unroll
      for (int C = 0; C < 4; C++){
        int c = col0 + 16*C + gma;
        float4v a = acc[R*4+C];
        float4 o;
        o.x = fmaxf(a[0]+bv.x, 0.f); o.y = fmaxf(a[1]+bv.y, 0.f);
        o.z = fmaxf(a[2]+bv.z, 0.f); o.w = fmaxf(a[3]+bv.w, 0.f);
        *(float4*)&Reps[(size_t)(bt0 + c)*384 + m*128 + r0] = o;
      }
    }
  }
}

// ---- mix: m=0 partial reduce + norms/softmax/phase, emit ps hi/lo bf16 ----
__global__ __launch_bounds__(128) void k_mix(const float* Rpart, const float* Reps,
    const float* bp0, const float* smask,
    const float* freq, const float* phem, ushort_t* PsH, ushort_t* PsL, float* Wgt)
{
  __shared__ float part[2][3];
  int bt = blockIdx.x; int t = bt % DT;
  int d = threadIdx.x;
  float r0v = bp0[d];
  #pragma unroll
  for (int ch = 0; ch < 6; ch++)
    r0v += Rpart[((size_t)ch*BT + bt)*128 + d];
  r0v = fmaxf(r0v, 0.f);
  float r1v = Reps[(size_t)bt*384 + 128 + d];
  float r2v = Reps[(size_t)bt*384 + 256 + d];
  float s0 = r0v*r0v, s1 = r1v*r1v, s2 = r2v*r2v;
  #pragma unroll
  for (int off = 1; off < 64; off <<= 1){
    s0 += __shfl_xor(s0, off, 64);
    s1 += __shfl_xor(s1, off, 64);
    s2 += __shfl_xor(s2, off, 64);
  }
  int wv = d >> 6;
  if ((d & 63) == 0){ part[wv][0] = s0; part[wv][1] = s1; part[wv][2] = s2; }
  __syncthreads();
  float n0 = sqrtf(part[0][0] + part[1][0]);
  float n1 = sqrtf(part[0][1] + part[1][1]);
  float n2 = sqrtf(part[0][2] + part[1][2]);
  float mx = fmaxf(n0, fmaxf(n1, n2));
  float e0 = expf(n0-mx), e1 = expf(n1-mx), e2 = expf(n2-mx);
  float einv = 1.f/(e0+e1+e2);
  if (d < 3) Wgt[bt*3+d] = (d==0?e0:(d==1?e1:e2))*einv;
  float sm0 = smask[bt*2], sm1 = smask[bt*2+1];
  int id = (sm1 > sm0) ? 1 : 0;
  float ph = (float)t * freq[id*DD+d] + phem[id*DD+d];
  float cp = cosf(ph), sp = sinf(ph);
  float a0 = r0v / fmaxf(n0, 1e-12f);
  float a1 = r1v / fmaxf(n1, 1e-12f);
  float a2 = r2v / fmaxf(n2, 1e-12f);
  ushort_t h, l;
  split2(a0*cp, h, l); PsH[((size_t)0*BT + bt)*DD + d] = h; PsL[((size_t)0*BT + bt)*DD + d] = l;
  split2(a1*cp, h, l); PsH[((size_t)1*BT + bt)*DD + d] = h; PsL[((size_t)1*BT + bt)*DD + d] = l;
  split2(a2*cp, h, l); PsH[((size_t)2*BT + bt)*DD + d] = h; PsL[((size_t)2*BT + bt)*DD + d] = l;
  split2(a0*sp, h, l); PsH[((size_t)3*BT + bt)*DD + d] = h; PsL[((size_t)3*BT + bt)*DD + d] = l;
  split2(a1*sp, h, l); PsH[((size_t)4*BT + bt)*DD + d] = h; PsL[((size_t)4*BT + bt)*DD + d] = l;
  split2(a2*sp, h, l); PsH[((size_t)5*BT + bt)*DD + d] = h; PsL[((size_t)5*BT + bt)*DD + d] = l;
}

// ---- qtrans v2: Q = ps @ Ux^T, + pow2 s=2 piggyback ----
__global__ __launch_bounds__(512,1) void k_qtrans(const ushort_t* UxH, const ushort_t* UxL,
                                                  const ushort_t* PsH, const ushort_t* PsL,
                                                  ushort_t* Qb,
                                                  ushort_t* PpH, ushort_t* PpL,
                                                  ushort_t* PTh, ushort_t* PTl){
  __shared__ ushort_t Ah[128*SP], Al[128*SP], Bh[128*SP], Bl[128*SP];
  int blk = blockIdx.x;
  int tid = threadIdx.x;
  if (blk >= 90){
    pow2_body(blk - 90, 2, PpH, PpL, PTh, PTl, tid, Ah, Al, Bh, Bl);
    return;
  }
  int w = tid >> 6, lane = tid & 63, gma = lane & 15, q = lane >> 4;
  int row0 = 32*(w >> 1), col0 = 64*(w & 1);
  size_t rbase = (size_t)blk*128*128;
  lds_load_mat<512>(Ah, UxH, tid);
  lds_load_mat<512>(Al, UxL, tid);
  lds_load_mat<512>(Bh, PsH + rbase, tid);
  lds_load_mat<512>(Bl, PsL + rbase, tid);
  __syncthreads();
  float4v acc[8];
  #pragma unroll
  for (int i = 0; i < 8; i++) acc[i] = (float4v){0.f,0.f,0.f,0.f};
  gemm_t<2,4,true,true>(Ah, Al, Bh, Bl, acc, row0, col0, gma, q);
  emit_t<2,4>(acc, Qb + rbase, 128, row0, col0, gma, q);
}

// ---- pow2v2: one squaring step, 16 blocks (standalone, s=3..5) ----
__global__ __launch_bounds__(256,2) void k_pow2v2(ushort_t* PpH, ushort_t* PpL,
                                                  ushort_t* PTh, ushort_t* PTl, int s){
  __shared__ ushort_t Ah[128*SP], Al[128*SP], Bh[16*SP], Bl[16*SP];
  int blk = blockIdx.x;
  int which = blk >> 3, sl = blk & 7;
  size_t src = (size_t)(s-1)*16384, dst = (size_t)s*16384;
  int tid = threadIdx.x;
  int w = tid >> 6, lane = tid & 63, gma = lane & 15, q = lane >> 4;
  int row0 = 32*w;
  int gcol0 = sl*16;
  const ushort_t *A_h, *A_l, *B_h, *B_l; ushort_t *D_h, *D_l;
  if (which == 0){ A_h = PTh+src; A_l = PTl+src; B_h = PpH+src; B_l = PpL+src;
                   D_h = PpH+dst; D_l = PpL+dst; }
  else           { A_h = PpH+src; A_l = PpL+src; B_h = PTh+src; B_l = PTl+src;
                   D_h = PTh+dst; D_l = PTl+dst; }
  lds_load_mat<256>(Ah, A_h, tid);
  lds_load_mat<256>(Al, A_l, tid);
  lds_load_rows16<256>(Bh, B_h + (size_t)gcol0*128, tid);
  lds_load_rows16<256>(Bl, B_l + (size_t)gcol0*128, tid);
  __syncthreads();
  float4v acc[2];
  acc[0] = (float4v){0.f,0.f,0.f,0.f};
  acc[1] = (float4v){0.f,0.f,0.f,0.f};
  gemm_t<2,1,true,true>(Ah, Al, Bh, Bl, acc, row0, 0, gma, q);
  emit_split_t<2,1>(acc, D_h, D_l, 128, row0, gcol0, gma, q);
}

// ---- gchain ----
__global__ __launch_bounds__(512,1) void k_gchain(const ushort_t* PpH, const ushort_t* PpL,
                                                  const ushort_t* PTh, const ushort_t* PTl,
                                                  ushort_t* GTh, ushort_t* GTl){
  __shared__ ushort_t Ah[128*SP], Al[128*SP], Bh[128*SP], Bl[128*SP];
  int t = blockIdx.x;
  int tid = threadIdx.x;
  int w = tid >> 6, lane = tid & 63, gma = lane & 15, q = lane >> 4;
  int row0 = 32*(w >> 1), col0 = 64*(w & 1);
  size_t gslot = (size_t)t * 16384;
  if (t == 0){
    for (int i = tid*4; i < 16384; i += 2048){
      int r = i >> 7, k = i & 127;
      ushort4 zz; zz.x = zz.y = zz.z = zz.w = 0;
      *(ushort4*)&GTl[gslot + i] = zz;
      ushort4 oh;
      oh.x = (r == (k+0)) ? (ushort_t)0x3F80 : (ushort_t)0;
      oh.y = (r == (k+1)) ? (ushort_t)0x3F80 : (ushort_t)0;
      oh.z = (r == (k+2)) ? (ushort_t)0x3F80 : (ushort_t)0;
      oh.w = (r == (k+3)) ? (ushort_t)0x3F80 : (ushort_t)0;
      *(ushort4*)&GTh[gslot + i] = oh;
    }
    return;
  }
  int b0 = __ffs(t) - 1;
  int rem = t & ~(1 << b0);
  if (rem == 0){
    size_t ps = (size_t)b0 * 16384;
    for (int i = tid*4; i < 16384; i += 2048){
      *(ushort4*)&GTh[gslot + i] = *(const ushort4*)&PTh[ps + i];
      *(ushort4*)&GTl[gslot + i] = *(const ushort4*)&PTl[ps + i];
    }
    return;
  }
  lds_load_mat<512>(Ah, PpH + (size_t)b0*16384, tid);
  lds_load_mat<512>(Al, PpL + (size_t)b0*16384, tid);
  while (rem){
    int k = __ffs(rem) - 1;
    rem &= ~(1 << k);
    lds_load_mat<512>(Bh, PTh + (size_t)k*16384, tid);
    lds_load_mat<512>(Bl, PTl + (size_t)k*16384, tid);
    __syncthreads();
    float4v acc[8];
    #pragma unroll
    for (int i = 0; i < 8; i++) acc[i] = (float4v){0.f,0.f,0.f,0.f};
    if (rem){
      gemm_t<2,4,true,true>(Bh, Bl, Ah, Al, acc, row0, col0, gma, q);
      __syncthreads();
      emit_split_t<2,4>(acc, Ah, Al, SP, row0, col0, gma, q);
      __syncthreads();
    } else {
      gemm_t<2,4,true,true>(Ah, Al, Bh, Bl, acc, row0, col0, gma, q);
      emit_split_t<2,4>(acc, GTh + gslot, GTl + gslot, 128, row0, col0, gma, q);
    }
  }
}

// ---- mwvt: precompMW (blk<180, tid<256 guarded) + vtrans (blk>=180) ----
__global__ __launch_bounds__(512,1) void k_mwvt(
    const ushort_t* GTh, const ushort_t* GTl,
    const ushort_t* UxTh, const ushort_t* UxTl,
    const float* Vr, const float* Vi,
    const ushort_t* Qb,
    ushort_t* Mh, ushort_t* Wh, ushort_t* At)
{
  __shared__ ushort_t LBUF[4*128*SP];
  int blk = blockIdx.x;
  int tid = threadIdx.x;
  if (blk < 180){
    ushort_t* Bh = LBUF;
    ushort_t* Bl = LBUF + 128*SP;
    ushort_t* Ah = LBUF + 2*128*SP;
    ushort_t* Al = LBUF + 3*128*SP;
    int w = tid >> 6, lane = tid & 63, gma = lane & 15, q = lane >> 4;
    int row0 = 64*(w >> 1), col0 = 64*(w & 1);
    if (blk < 60){
      int t = blk;
      if (tid < 256){
        lds_load_mat<256>(Bh, GTh + (size_t)t*16384, tid);
        lds_load_mat<256>(Bl, GTl + (size_t)t*16384, tid);
        lds_load_mat<256>(Ah, UxTh, tid);
        lds_load_mat<256>(Al, UxTl, tid);
      }
      __syncthreads();
      float4v acc[16];
      if (tid < 256){
        #pragma unroll
        for (int i = 0; i < 16; i++) acc[i] = (float4v){0.f,0.f,0.f,0.f};
        gemm_t<4,4,true,true>(Ah, Al, Bh, Bl, acc, row0, col0, gma, q);
      }
      __syncthreads();
      if (tid < 256) emit_split_t<4,4>(acc, Ah, Al, SP, row0, col0, gma, q);
      __syncthreads();
      if (tid < 256){
        #pragma unroll
        for (int i = 0; i < 16; i++) acc[i] = (float4v){0.f,0.f,0.f,0.f};
        gemm_t<4,4,true,true>(Bh, Bl, Ah, Al, acc, row0, col0, gma, q);
        #pragma unroll
        for (int R = 0; R < 4; R++)
          #pragma unroll
          for (int C = 0; C < 4; C++){
            int c = col0 + 16*C + gma, r0 = row0 + 16*R + 4*q;
            uint2 o;
            o.x = f2bfpk(acc[R*4+C][0], acc[R*4+C][1]);
            o.y = f2bfpk(acc[R*4+C][2], acc[R*4+C][3]);
            *(uint2*)&Mh[(size_t)t*16384 + c*128 + r0] = o;
          }
      }
    } else {
      int bx = blk - 60;
      int t = bx >> 1, which = bx & 1;
      if (tid < 256){
        lds_load_mat<256>(Ah, GTh + (size_t)t*16384, tid);
        lds_load_mat<256>(Al, GTl + (size_t)t*16384, tid);
        const float* V = which ? Vi : Vr;
        for (int i = tid; i < 16384; i += 256){
          int r = i >> 7, k = i & 127;
          ushort_t h, l; split2(V[i], h, l);
          Bh[r*SP + k] = h; Bl[r*SP + k] = l;
        }
      }
      __syncthreads();
      if (tid < 256){
        float4v acc[16];
        #pragma unroll
        for (int i = 0; i < 16; i++) acc[i] = (float4v){0.f,0.f,0.f,0.f};
        gemm_t<4,4,true,true>(Ah, Al, Bh, Bl, acc, row0, col0, gma, q);
        #pragma unroll
        for (int R = 0; R < 4; R++)
          #pragma unroll
          for (int C = 0; C < 4; C++){
            int c = col0 + 16*C + gma, r0 = row0 + 16*R + 4*q;
            uint2 o;
            o.x = f2bfpk(acc[R*4+C][0], acc[R*4+C][1]);
            o.y = f2bfpk(acc[R*4+C][2], acc[R*4+C][3]);
            *(uint2*)&Wh[(size_t)bx*16384 + c*128 + r0] = o;
          }
      }
    }
  } else {
    // vtrans: per t, A'[j,b] = G_t^T q_{j,b}
    ushort_t* Ah = LBUF;                 // 128*SP
    ushort_t* Bs = LBUF + 128*SP;        // 192*SP (fits in remaining 3*128*SP)
    int t = blk - 180;
    int w = tid >> 6, lane = tid & 63, gma = lane & 15, q = lane >> 4;
    int row0 = (w & 3)*32, col0 = (w >> 2)*96;
    lds_load_mat<512>(Ah, GTh + (size_t)t*16384, tid);
    for (int i = tid*8; i < 192*128; i += 4096){
      int m = i >> 7, k = i & 127;
      int j = m >> 5, b = m & 31;
      *(ushort8_t*)&Bs[m*SP + k] =
        *(const ushort8_t*)&Qb[((size_t)(j*BT) + b*DT + t)*DD + k];
    }
    __syncthreads();
    float4v acc[12];
    #pragma unroll
    for (int i = 0; i < 12; i++) acc[i] = (float4v){0.f,0.f,0.f,0.f};
    gemm_t<2,6,false,false>(Ah, Ah, Bs, Bs, acc, row0, col0, gma, q);
    emit_t<2,6>(acc, At + (size_t)t*24576, 128, row0, col0, gma, q);
  }
}

// ---- zbuild v2: rank-6 Y build + lambda-prefix, latency-hidden ----
__global__ __launch_bounds__(256) void k_zbuild(ushort_t* S, const ushort_t* At,
                                                const float* Wgt, const float* lamp){
  __shared__ ushort_t As[2][6*DD];
  __shared__ float wl[2][3];
  int blk = blockIdx.x;
  int b = blk >> 5, sl2 = blk & 31;
  int tid = threadIdx.x;
  int r = sl2*4 + (tid >> 6);
  int c = (tid*2) & 127;
  float lam = lamp[0];
  float z0 = 0.f, z1 = 0.f;
  size_t off = (size_t)sl2*512 + tid*2;
  ushort4 pre;
  float wpre = 0.f;
  int jj0 = 0, n0 = 0;
  if (tid < 192){
    int i = tid*4;
    jj0 = i >> 7; n0 = i & 127;
    pre = *(const ushort4*)&At[(size_t)(jj0*32 + b)*128 + n0];
  }
  if (tid < 3) wpre = Wgt[(b*DT)*3 + tid];
  for (int t = 0; t < DT; t++){
    int cur = t & 1;
    if (tid < 192) *(ushort4*)&As[cur][tid*4] = pre;
    if (tid < 3) wl[cur][tid] = wpre;
    __syncthreads();
    if (t+1 < DT){
      if (tid < 192)
        pre = *(const ushort4*)&At[(size_t)(t+1)*24576 + (size_t)(jj0*32 + b)*128 + n0];
      if (tid < 3) wpre = Wgt[(b*DT + t+1)*3 + tid];
    }
    float ar[6];
    #pragma unroll
    for (int jj = 0; jj < 6; jj++) ar[jj] = bf2f(As[cur][jj*128 + r]);
    float w0 = wl[cur][0], w1 = wl[cur][1], w2 = wl[cur][2];
    float cb[6];
    cb[0] = w0*(ar[0]+ar[3]); cb[1] = w1*(ar[1]+ar[4]); cb[2] = w2*(ar[2]+ar[5]);
    cb[3] = w0*(ar[3]-ar[0]); cb[4] = w1*(ar[4]-ar[1]); cb[5] = w2*(ar[5]-ar[2]);
    float y0 = 0.f, y1 = 0.f;
    #pragma unroll
    for (int jj = 0; jj < 6; jj++){
      unsigned int a2 = *(const unsigned int*)&As[cur][jj*128 + c];
      float w_ = cb[jj];
      y0 += w_*bf2f((ushort_t)(a2 & 0xFFFF));
      y1 += w_*bf2f((ushort_t)(a2 >> 16));
    }
    z0 = lam*z0 + y0; z1 = lam*z1 + y1;
    *(unsigned int*)&S[((size_t)(t*32 + b))*16384 + off] = f2bfpk(z0, z1);
  }
}

// ---- conjmid v2 (512 thr, per (t, 4-b group)): M staged once, 4 b's ----
__global__ __launch_bounds__(512,2) void k_conjmid(ushort_t* S, const ushort_t* Mh,
                                                   const float* lamp){
  __shared__ ushort_t Bh[128*SP], Zs[128*SP];
  int raw = blockIdx.x;            // 480 = 60 t x 8 g
  int g = raw & 7, t = raw >> 3;
  int tid = threadIdx.x;
  int w = tid >> 6, lane = tid & 63, gma = lane & 15, q = lane >> 4;
  int row0 = 32*(w >> 1), col0 = 64*(w & 1);
  size_t slot0 = (size_t)(t*32 + g*4) * 16384;
  lds_load_mat2<512>(Zs, S + slot0, Bh, Mh + (size_t)t*16384, tid);
  __syncthreads();
  float lam = lamp[0];
  float oml = 1.f - lam;
  float ct = powf(lam, (float)(t+1)) / 128.f;
  for (int ib = 0; ib < 4; ib++){
    size_t slot = slot0 + (size_t)ib*16384;
    ushort8_t znext[4];
    if (ib < 3){
      #pragma unroll
      for (int c = 0; c < 4; c++)
        znext[c] = *(const ushort8_t*)&S[slot + 16384 + tid*8 + c*4096];
    }
    float4v acc[8];
    #pragma unroll
    for (int i = 0; i < 8; i++) acc[i] = (float4v){0.f,0.f,0.f,0.f};
    gemm_t<2,4,false,false>(Zs, Zs, Bh, Bh, acc, row0, col0, gma, q);
    __syncthreads();
    emit_t<2,4>(acc, Zs, SP, row0, col0, gma, q);
    __syncthreads();
    #pragma unroll
    for (int i = 0; i < 8; i++) acc[i] = (float4v){0.f,0.f,0.f,0.f};
    gemm_t<2,4,false,false>(Zs, Zs, Bh, Bh, acc, row0, col0, gma, q);
    __syncthreads();
    #pragma unroll
    for (int R = 0; R < 2; R++)
      #pragma unroll
      for (int C = 0; C < 4; C++){
        int c = col0 + 16*C + gma, r0 = row0 + 16*R + 4*q;
        float v0 = oml*acc[R*4+C][0] + ((c == r0+0) ? ct : 0.f);
        float v1 = oml*acc[R*4+C][1] + ((c == r0+1) ? ct : 0.f);
        float v2 = oml*acc[R*4+C][2] + ((c == r0+2) ? ct : 0.f);
        float v3 = oml*acc[R*4+C][3] + ((c == r0+3) ? ct : 0.f);
        uint2 o; o.x = f2bfpk(v0, v1); o.y = f2bfpk(v2, v3);
        *(uint2*)&Zs[(size_t)c*SP + r0] = o;
      }
    __syncthreads();
    lds_store_mat<512>(S + slot, Zs, tid);
    if (ib < 3){
      __syncthreads();
      #pragma unroll
      for (int c = 0; c < 4; c++){
        int i = tid*8 + c*4096;
        int r = i >> 7, k = i & 127;
        *(ushort8_t*)&Zs[r*SP + k] = znext[c];
      }
      __syncthreads();
    }
  }
}

// ---- prefix v3: 1024 blk (32 chains x 32 slabs), 8B/lane, depth-6 ----
__device__ __forceinline__ void prefix_ph2(uint2& buf, bool doload,
                                           const ushort_t* Snext, ushort_t* Scur,
                                           float* a, float lam){
  uint2 u = buf;
  if (doload) buf = *(const uint2*)Snext;
  a[0] = lam*a[0] + bf2f((ushort_t)(u.x & 0xFFFF));
  a[1] = lam*a[1] + bf2f((ushort_t)(u.x >> 16));
  a[2] = lam*a[2] + bf2f((ushort_t)(u.y & 0xFFFF));
  a[3] = lam*a[3] + bf2f((ushort_t)(u.y >> 16));
  uint2 o;
  o.x = f2bfpk(a[0], a[1]); o.y = f2bfpk(a[2], a[3]);
  *(uint2*)Scur = o;
}
__global__ __launch_bounds__(128) void k_prefix(ushort_t* S, const float* lamp){
  int blk = blockIdx.x;            // 1024 = 32 chains x 32 slabs
  int chain = blk >> 5, slab = blk & 31;
  int tid = threadIdx.x;
  size_t off = (size_t)slab*512 + tid*4;
  float lam = lamp[0];
  float a[4];
  #pragma unroll
  for (int i = 0; i < 4; i++) a[i] = 0.f;
  size_t addr = (size_t)chain*16384 + off;
  const size_t step = (size_t)32*16384;
  uint2 b0 = *(const uint2*)&S[addr];
  uint2 b1 = *(const uint2*)&S[addr + step];
  uint2 b2 = *(const uint2*)&S[addr + 2*step];
  uint2 b3 = *(const uint2*)&S[addr + 3*step];
  uint2 b4 = *(const uint2*)&S[addr + 4*step];
  uint2 b5 = *(const uint2*)&S[addr + 5*step];
  for (int t = 0; t < DT; t += 6){
    prefix_ph2(b0, t+6  < DT, &S[addr + 6*step], &S[addr], a, lam); addr += step;
    prefix_ph2(b1, t+7  < DT, &S[addr + 6*step], &S[addr], a, lam); addr += step;
    prefix_ph2(b2, t+8  < DT, &S[addr + 6*step], &S[addr], a, lam); addr += step;
    prefix_ph2(b3, t+9  < DT, &S[addr + 6*step], &S[addr], a, lam); addr += step;
    prefix_ph2(b4, t+10 < DT, &S[addr + 6*step], &S[addr], a, lam); addr += step;
    prefix_ph2(b5, t+11 < DT, &S[addr + 6*step], &S[addr], a, lam); addr += step;
  }
}

// ---- meas v7 (512 thr, per (t,h,8-b group)): V staged ONCE, loop 8 b's;
// raw = h*240 + t*4 + g so h-siblings share XCD (240 % 8 == 0). ----
__global__ __launch_bounds__(512,2) void k_meas(const ushort_t* S, const ushort_t* Wh,
                                                const float* lamp, float* Probs){
  __shared__ ushort_t Vs[128*SP], Cs[128*SP];
  __shared__ float Pd[64];
  int raw = blockIdx.x;            // 480 = 2 h x (60 t x 4 g)
  int h = raw / 240;
  int rem = raw % 240;
  int t = rem >> 2, g = rem & 3;
  int tid = threadIdx.x;
  int w = tid >> 6, lane = tid & 63, gma = lane & 15, q = lane >> 4;
  int row0 = 16*(w >> 1);
  int col0 = 64*(w & 1);
  size_t wbase = (size_t)(t*2) * 16384;
  size_t slot0 = (size_t)(t*32 + g*8) * 16384;
  ushort8_t creg[4], vreg[4];
  #pragma unroll
  for (int c = 0; c < 4; c++)
    creg[c] = *(const ushort8_t*)&S[slot0 + tid*8 + c*4096];
  #pragma unroll
  for (int c = 0; c < 4; c++){
    int i = tid*8 + c*4096;
    int r = i >> 7, k = i & 127;
    size_t gsrc = wbase + ((r < 64) ? 0 : 16384) + (size_t)(64*h + (r & 63))*128 + k;
    vreg[c] = *(const ushort8_t*)&Wh[gsrc];
  }
  if (tid < 64) Pd[tid] = 0.f;
  #pragma unroll
  for (int c = 0; c < 4; c++){
    int i = tid*8 + c*4096;
    int r = i >> 7, k = i & 127;
    *(ushort8_t*)&Cs[r*SP + k] = creg[c];
    *(ushort8_t*)&Vs[r*SP + k] = vreg[c];
  }
  __syncthreads();
  float lam = lamp[0];
  float ct = powf(lam, (float)(t+1)) / 128.f;
  for (int ib = 0; ib < 8; ib++){
    if (ib < 7){
      size_t snx = slot0 + (size_t)(ib+1)*16384;
      #pragma unroll
      for (int c = 0; c < 4; c++)
        creg[c] = *(const ushort8_t*)&S[snx + tid*8 + c*4096];
    }
    float4v acc[8];
    #pragma unroll
    for (int i = 0; i < 8; i++) acc[i] = (float4v){0.f,0.f,0.f,0.f};
    #pragma unroll
    for (int ks = 0; ks < 4; ks++){
      int ko = ks*32 + q*8;
      bf16x8 aF0 = *(const bf16x8*)&Vs[(row0 + gma)*SP + ko];
      bf16x8 aF1 = *(const bf16x8*)&Vs[(row0 + 64 + gma)*SP + ko];
      bf16x8 bF[4];
      #pragma unroll
      for (int C = 0; C < 4; C++)
        bF[C] = *(const bf16x8*)&Cs[(col0 + 16*C + gma)*SP + ko];
      #pragma unroll
      for (int C = 0; C < 4; C++){
        acc[C]   = __builtin_amdgcn_mfma_f32_16x16x32_bf16(aF0, bF[C], acc[C],   0, 0, 0);
        acc[4+C] = __builtin_amdgcn_mfma_f32_16x16x32_bf16(aF1, bF[C], acc[4+C], 0, 0, 0);
      }
    }
    #pragma unroll
    for (int j = 0; j < 4; j++){
      int kr = row0 + 4*q + j;
      float s = 0.f;
      #pragma unroll
      for (int C = 0; C < 4; C++){
        int m = col0 + 16*C + gma;
        float w0 = bf2f(Vs[kr*SP + m]);
        float w1 = bf2f(Vs[(kr + 64)*SP + m]);
        s += acc[C][j]*(w0 + w1) + acc[4+C][j]*(w1 - w0);
      }
      #pragma unroll
      for (int off = 1; off < 16; off <<= 1)
        s += __shfl_xor(s, off, 64);
      if (gma == 0) atomicAdd(&Pd[kr], s);
    }
    __syncthreads();
    if (tid < 64){
      Probs[(size_t)(t*32 + g*8 + ib)*DD + 64*h + tid] = (1.f - lam)*Pd[tid] + ct;
      Pd[tid] = 0.f;
    }
    if (ib < 7){
      #pragma unroll
      for (int c = 0; c < 4; c++){
        int i = tid*8 + c*4096;
        int r = i >> 7, k = i & 127;
        *(ushort8_t*)&Cs[r*SP + k] = creg[c];
      }
    }
    __syncthreads();
  }
}

// ---- head ----
__global__ __launch_bounds__(64) void k_head(const float* Probs, const float* W1, const float* b1,
                        const float* W2, const float* b2, float* out)
{
  __shared__ float ps[DD];
  __shared__ float hid[64];
  __shared__ float ov[4];
  int tb = blockIdx.x;
  int tid = threadIdx.x;
  ps[tid] = Probs[(size_t)tb*DD + tid];
  ps[tid+64] = Probs[(size_t)tb*DD + 64 + tid];
  __syncthreads();
  float acc = b1[tid];
  for (int dd = 0; dd < DD; dd++) acc += ps[dd]*W1[dd*64 + tid];
  hid[tid] = fmaxf(acc, 0.f);
  __syncthreads();
  if (tid < 4){
    float o = b2[tid];
    for (int j = 0; j < 64; j++) o += hid[j]*W2[j*4 + tid];
    ov[tid] = tanhf(o);
  }
  __syncthreads();
  if (tid == 0){
    float m = fmaxf(fmaxf(ov[0],ov[1]), fmaxf(ov[2],ov[3]));
    float lse = logf(expf(ov[0]-m)+expf(ov[1]-m)+expf(ov[2]-m)+expf(ov[3]-m));
    int t = tb >> 5, b = tb & 31;
    float* o = out + ((size_t)(b*DT + t))*4;
    o[0] = ov[0]-m-lse; o[1] = ov[1]-m-lse;
    o[2] = ov[2]-m-lse; o[3] = ov[3]-m-lse;
  }
}

extern "C" void kernel_launch(void* const* d_in, const int* in_sizes, int n_in,
                              void* d_out, int out_size, void* d_ws, size_t ws_size,
                              hipStream_t stream)
{
  const float* x0    = (const float*)d_in[0];
  const float* x1    = (const float*)d_in[1];
  const float* x2    = (const float*)d_in[2];
  const float* smask = (const float*)d_in[3];
  const float* Wp0   = (const float*)d_in[4];
  const float* bp0   = (const float*)d_in[5];
  const float* Wp1   = (const float*)d_in[6];
  const float* bp1   = (const float*)d_in[7];
  const float* Wp2   = (const float*)d_in[8];
  const float* bp2   = (const float*)d_in[9];
  const float* freq  = (const float*)d_in[10];
  const float* phem  = (const float*)d_in[11];
  const float* Ux    = (const float*)d_in[12];
  const float* Uh    = (const float*)d_in[13];
  const float* lamp  = (const float*)d_in[14];
  const float* kr    = (const float*)d_in[15];
  const float* ki    = (const float*)d_in[16];
  const float* W1    = (const float*)d_in[17];
  const float* b1    = (const float*)d_in[18];
  const float* W2    = (const float*)d_in[19];
  const float* b2    = (const float*)d_in[20];

  char* ws = (char*)d_ws;
  auto alignup = [](size_t x){ return (x + 255) & ~(size_t)255; };
  size_t off = 0;
  ushort_t* S   = (ushort_t*)(ws + off); off = alignup(off + (size_t)1920*16384*sizeof(ushort_t));
  ushort_t* Qb  = (ushort_t*)(ws + off); off = alignup(off + (size_t)6*BT*DD*sizeof(ushort_t));
  float* Rpart  = (float*)(ws + off);    off = alignup(off + (size_t)6*BT*DD*sizeof(float));
  float* Reps   = (float*)(ws + off);    off = alignup(off + (size_t)BT*384*sizeof(float));
  ushort_t* PsH = (ushort_t*)(ws + off); off = alignup(off + (size_t)6*BT*DD*sizeof(ushort_t));
  ushort_t* PsL = (ushort_t*)(ws + off); off = alignup(off + (size_t)6*BT*DD*sizeof(ushort_t));
  ushort_t* X0h = (ushort_t*)(ws + off); off = alignup(off + (size_t)BT*768*sizeof(ushort_t));
  ushort_t* X0l = (ushort_t*)(ws + off); off = alignup(off + (size_t)BT*768*sizeof(ushort_t));
  ushort_t* X1h = (ushort_t*)(ws + off); off = alignup(off + (size_t)BT*128*sizeof(ushort_t));
  ushort_t* X1l = (ushort_t*)(ws + off); off = alignup(off + (size_t)BT*128*sizeof(ushort_t));
  ushort_t* X2h = (ushort_t*)(ws + off); off = alignup(off + (size_t)BT*128*sizeof(ushort_t));
  ushort_t* X2l = (ushort_t*)(ws + off); off = alignup(off + (size_t)BT*128*sizeof(ushort_t));
  float* Wgt    = (float*)(ws + off);    off = alignup(off + (size_t)BT*3*sizeof(float));
  float* Vr     = (float*)(ws + off);    off = alignup(off + (size_t)DD*DD*sizeof(float));
  float* Vi     = (float*)(ws + off);    off = alignup(off + (size_t)DD*DD*sizeof(float));
  ushort_t* UxTh = (ushort_t*)(ws + off); off = alignup(off + (size_t)DD*DD*sizeof(ushort_t));
  ushort_t* UxTl = (ushort_t*)(ws + off); off = alignup(off + (size_t)DD*DD*sizeof(ushort_t));
  ushort_t* UxH = (ushort_t*)(ws + off); off = alignup(off + (size_t)DD*DD*sizeof(ushort_t));
  ushort_t* UxL = (ushort_t*)(ws + off); off = alignup(off + (size_t)DD*DD*sizeof(ushort_t));
  float* Probs  = (float*)(ws + off);    off = alignup(off + (size_t)BT*DD*sizeof(float));
  ushort_t* PpH = (ushort_t*)(ws + off); off = alignup(off + (size_t)6*16384*sizeof(ushort_t));
  ushort_t* PpL = (ushort_t*)(ws + off); off = alignup(off + (size_t)6*16384*sizeof(ushort_t));
  ushort_t* PTh = (ushort_t*)(ws + off); off = alignup(off + (size_t)6*16384*sizeof(ushort_t));
  ushort_t* PTl = (ushort_t*)(ws + off); off = alignup(off + (size_t)6*16384*sizeof(ushort_t));
  ushort_t* Mh  = (ushort_t*)(ws + off); off = alignup(off + (size_t)60*16384*sizeof(ushort_t));
  ushort_t* Wmh = (ushort_t*)(ws + off); off = alignup(off + (size_t)120*16384*sizeof(ushort_t));
  ushort_t* GTh = (ushort_t*)(ws + off); off = alignup(off + (size_t)60*16384*sizeof(ushort_t));
  ushort_t* GTl = (ushort_t*)(ws + off); off = alignup(off + (size_t)60*16384*sizeof(ushort_t));
  ushort_t* At  = (ushort_t*)(ws + off); off = alignup(off + (size_t)60*24576*sizeof(ushort_t));
  ushort_t* WT0h = (ushort_t*)(ws + off); off = alignup(off + (size_t)128*768*sizeof(ushort_t));
  ushort_t* WT0l = (ushort_t*)(ws + off); off = alignup(off + (size_t)128*768*sizeof(ushort_t));
  ushort_t* WT1h = (ushort_t*)(ws + off); off = alignup(off + (size_t)128*128*sizeof(ushort_t));
  ushort_t* WT1l = (ushort_t*)(ws + off); off = alignup(off + (size_t)128*128*sizeof(ushort_t));
  ushort_t* WT2h = (ushort_t*)(ws + off); off = alignup(off + (size_t)128*128*sizeof(ushort_t));
  ushort_t* WT2l = (ushort_t*)(ws + off); off = alignup(off + (size_t)128*128*sizeof(ushort_t));
  (void)ws_size; (void)in_sizes; (void)n_in; (void)out_size;

  k_small<<<512 + BT, 128, 0, stream>>>(Ux, Uh, kr, ki, Wp0, Wp1, Wp2, x0, x1, x2,
                                        UxTh, UxTl, UxH, UxL, Vr, Vi,
                                        PpH, PpL, PTh, PTl,
                                        WT0h, WT0l, WT1h, WT1l, WT2h, WT2l,
                                        X0h, X0l, X1h, X1l, X2h, X2l);
  k_proj<<<136, 512, 0, stream>>>(X0h, X0l, X1h, X1l, X2h, X2l,
                                  WT0h, WT0l, WT1h, WT1l, WT2h, WT2l,
                                  bp1, bp2, Rpart, Reps, PpH, PpL, PTh, PTl);
  k_mix<<<BT, 128, 0, stream>>>(Rpart, Reps, bp0, smask, freq, phem, PsH, PsL, Wgt);
  k_qtrans<<<106, 512, 0, stream>>>(UxH, UxL, PsH, PsL, Qb, PpH, PpL, PTh, PTl);
  for (int s = 3; s <= 5; s++)
    k_pow2v2<<<16, 256, 0, stream>>>(PpH, PpL, PTh, PTl, s);
  k_gchain<<<60, 512, 0, stream>>>(PpH, PpL, PTh, PTl, GTh, GTl);
  k_mwvt<<<240, 512, 0, stream>>>(GTh, GTl, UxTh, UxTl, Vr, Vi, Qb, Mh, Wmh, At);
  k_zbuild<<<1024, 256, 0, stream>>>(S, At, Wgt, lamp);
  k_conjmid<<<480, 512, 0, stream>>>(S, Mh, lamp);
  k_prefix<<<1024, 128, 0, stream>>>(S, lamp);
  k_meas<<<480, 512, 0, stream>>>(S, Wmh, lamp, Probs);
  k_head<<<BT, 64, 0, stream>>>(Probs, W1, b1, W2, b2, (float*)d_out);
}